// Round 20
// baseline (112.055 us; speedup 1.0000x reference)
//
#include <hip/hip_runtime.h>

#define NN 2048
#define NH 8
#define NTASK 2368

typedef __attribute__((ext_vector_type(4))) short s4;
typedef __attribute__((ext_vector_type(8))) short s8;
typedef __attribute__((ext_vector_type(4))) float f4;

static __device__ __forceinline__ ushort f2b(float x) {
    uint u = __builtin_bit_cast(uint, x);
    uint r = (u + 0x7FFFu + ((u >> 16) & 1u)) >> 16;
    return (ushort)r;
}
static __device__ __forceinline__ float b2f(ushort b) {
    return __builtin_bit_cast(float, ((uint)b) << 16);
}
static __device__ __forceinline__ uint pu(ushort a, ushort b) {
    return (uint)a | ((uint)b << 16);
}
// Pure-C bf16x2 pack (RNE). NO inline asm anywhere (rounds 4-10's NaNs were
// an inline-asm producer -> MFMA hazard lottery; builtin-only is safe).
static __device__ __forceinline__ uint bpack(float lo, float hi) {
    return pu(f2b(lo), f2b(hi));
}
static __device__ __forceinline__ s4 pack4(float a, float b, float c, float d) {
    uint2 w; w.x = bpack(a, b); w.y = bpack(c, d);
    return __builtin_bit_cast(s4, w);
}
static __device__ __forceinline__ f4 mfma32(s8 a, s8 b, f4 c) {
    return __builtin_amdgcn_mfma_f32_16x16x32_bf16(a, b, c, 0, 0, 0);
}
static __device__ __forceinline__ f4 mfma16(s4 a, s4 b, f4 c) {
    const s4 z4s = {0, 0, 0, 0};
    s8 a8 = __builtin_shufflevector(a, z4s, 0, 1, 2, 3, 4, 5, 6, 7);
    s8 b8 = __builtin_shufflevector(b, z4s, 0, 1, 2, 3, 4, 5, 6, 7);
    return __builtin_amdgcn_mfma_f32_16x16x32_bf16(a8, b8, c, 0, 0, 0);
}

// Shared task table: weight row base + length for task r (must match proj).
static __device__ __forceinline__ const float* task_wrow(
    int r, int& len,
    const float* W_ak, const float* W_vk, const float* W_aq, const float* W_vq,
    const float* W_aval, const float* W_vval, const float* W_a2vval,
    const float* W_v2aval)
{
    if (r < 256)       { len = 128; return W_ak + r * 128; }
    else if (r < 512)  { len = 128; return W_aq + (r - 256) * 128; }
    else if (r < 896)  { int q = r - 512;  int h = q / 48; int s = q - h * 48; len = 64; return W_vk + (h * 16 + s / 3) * 64; }
    else if (r < 1280) { int q = r - 896;  int h = q / 48; int s = q - h * 48; len = 64; return W_vq + (h * 16 + s / 3) * 64; }
    else if (r < 1408) { len = 128; return W_aval + (r - 1280) * 128; }
    else if (r < 1600) { int q = r - 1408; int h = q / 24; int s = q - h * 24; len = 64; return W_vval + (h * 8 + s / 3) * 64; }
    else if (r < 1984) { int q = r - 1600; int h = q / 48; int s = q - h * 48; len = 64; return W_v2aval + (h * 16 + s / 3) * 64; }
    else if (r < 2048) { len = 128; return W_a2vval + (r - 1984) * 128; }
    else if (r < 2176) { int q = r - 2048; int h = q >> 4; len = 64; return W_v2aval + (h * 16 + (q & 15)) * 64; }
    else               { int q = r - 2176; int h = q / 24; int s = q - h * 24; int i = s / 3; len = 128; return W_a2vval + (h * 8 + i) * 128; }
}

// ---------------------------------------------------------------------------
// Kernel 0: weight transpose. Wt[j][r] (stride NTASK), coalesced writes.
// Entries with j >= len(r) are never read downstream (left as-is).
// ---------------------------------------------------------------------------
__global__ __launch_bounds__(256) void wtrans_kernel(
    const float* __restrict__ W_ak, const float* __restrict__ W_vk,
    const float* __restrict__ W_aq, const float* __restrict__ W_vq,
    const float* __restrict__ W_aval, const float* __restrict__ W_vval,
    const float* __restrict__ W_a2vval, const float* __restrict__ W_v2aval,
    float* __restrict__ Wt)
{
    int g = blockIdx.x * 256 + threadIdx.x;
    if (g >= NTASK * 128) return;
    int j = g / NTASK, r = g - j * NTASK;
    int len;
    const float* wrow = task_wrow(r, len, W_ak, W_vk, W_aq, W_vq,
                                  W_aval, W_vval, W_a2vval, W_v2aval);
    if (j < len) Wt[(size_t)j * NTASK + r] = wrow[j];
}

// ---------------------------------------------------------------------------
// Kernel A: merged proj+finish+vtrans (R15 structure), weights now read from
// the transposed Wt: lane reads Wt[j*NTASK + r] with r = rr*512+t ->
// consecutive lanes, consecutive addresses -> coalesced (16x fewer L2 reqs).
// ---------------------------------------------------------------------------
__global__ __launch_bounds__(512) void proj_kernel(
    const float* __restrict__ ax, const float* __restrict__ vx,
    const float* __restrict__ pos_k, const float* __restrict__ pos_q,
    const float* __restrict__ Wt,
    ushort* __restrict__ Kf, ushort* __restrict__ Qf, ushort* __restrict__ Vt)
{
    __shared__ float axs[8][128];
    __shared__ float vxs[3][8][64];
    __shared__ float xts[8][64];
    __shared__ float pqs[8][3];
    __shared__ __align__(16) ushort kqs[2][8][8][80];   // [dst][node][head][col]
    const int t  = threadIdx.x;
    const int n0 = blockIdx.x * 8;

    for (int idx = t; idx < 1024; idx += 512)
        axs[idx >> 7][idx & 127] = ax[n0 * 128 + idx];
    for (int idx = t; idx < 1536; idx += 512) {
        int nb = idx / 192, r = idx - nb * 192;
        int j = r / 3, v = r - j * 3;
        vxs[v][nb][j] = vx[n0 * 192 + idx];
    }
    if (t < 24) pqs[t / 3][t % 3] = pos_q[n0 * 3 + t];
    __syncthreads();
    {
        int nb = t >> 6, j = t & 63;
        xts[nb][j] = vxs[0][nb][j] * pqs[nb][0] + vxs[1][nb][j] * pqs[nb][1]
                   + vxs[2][nb][j] * pqs[nb][2];
    }
    __syncthreads();

    #pragma unroll 1
    for (int rr = 0; rr < 5; ++rr) {
        int r = rr * 512 + t;
        if (r >= NTASK) continue;
        int h, v = 0, col = -1, vrow = -1, dsti = 0, srcT = 0, pv = -1;
        float scale = 1.0f;
        if (r < 256)       { int q = r;        h = q >> 5; srcT = 0; col = q & 31; dsti = 0; }
        else if (r < 512)  { int q = r - 256;  h = q >> 5; srcT = 0; col = q & 31; dsti = 1; scale = 0.1f; }
        else if (r < 896)  { int q = r - 512;  h = q / 48; int s = q - h * 48; v = s % 3; srcT = 1; col = 32 + s; dsti = 0; }
        else if (r < 1280) { int q = r - 896;  h = q / 48; int s = q - h * 48; v = s % 3; srcT = 1; col = 32 + s; dsti = 1; scale = 0.1f; }
        else if (r < 1408) { int q = r - 1280; h = q >> 4; srcT = 0; vrow = q & 15; }
        else if (r < 1600) { int q = r - 1408; h = q / 24; int s = q - h * 24; v = s % 3; srcT = 1; vrow = 16 + s; }
        else if (r < 1984) { int q = r - 1600; h = q / 48; int s = q - h * 48; v = s % 3; srcT = 1; vrow = 48 + s; }
        else if (r < 2048) { int q = r - 1984; h = q >> 3; srcT = 0; vrow = 112 + (q & 7); }
        else if (r < 2176) { int q = r - 2048; h = q >> 4; srcT = 2; vrow = 96 + (q & 15); }
        else               { int q = r - 2176; h = q / 24; int s = q - h * 24; pv = s % 3; srcT = 0; vrow = 120 + s; }

        const float* Wc = Wt + r;   // column base; row j at Wc[j*NTASK]
        float acc[8] = {0.f, 0.f, 0.f, 0.f, 0.f, 0.f, 0.f, 0.f};
        if (srcT == 0) {
            for (int j = 0; j < 128; j += 4) {
                float w0 = Wc[(size_t)(j + 0) * NTASK];
                float w1 = Wc[(size_t)(j + 1) * NTASK];
                float w2 = Wc[(size_t)(j + 2) * NTASK];
                float w3 = Wc[(size_t)(j + 3) * NTASK];
                #pragma unroll
                for (int nb = 0; nb < 8; ++nb) {
                    float4 x4 = *(const float4*)(&axs[nb][j]);
                    acc[nb] += w0 * x4.x + w1 * x4.y + w2 * x4.z + w3 * x4.w;
                }
            }
        } else {
            const float* sp = (srcT == 1) ? &vxs[v][0][0] : &xts[0][0];
            for (int j = 0; j < 64; j += 4) {
                float w0 = Wc[(size_t)(j + 0) * NTASK];
                float w1 = Wc[(size_t)(j + 1) * NTASK];
                float w2 = Wc[(size_t)(j + 2) * NTASK];
                float w3 = Wc[(size_t)(j + 3) * NTASK];
                #pragma unroll
                for (int nb = 0; nb < 8; ++nb) {
                    float4 x4 = *(const float4*)(sp + nb * 64 + j);
                    acc[nb] += w0 * x4.x + w1 * x4.y + w2 * x4.z + w3 * x4.w;
                }
            }
        }
        if (vrow >= 0) {
            float o[8];
            #pragma unroll
            for (int nb = 0; nb < 8; ++nb)
                o[nb] = acc[nb] * (pv >= 0 ? pqs[nb][pv] : 1.0f);
            uint4 pk;
            pk.x = bpack(o[0], o[1]); pk.y = bpack(o[2], o[3]);
            pk.z = bpack(o[4], o[5]); pk.w = bpack(o[6], o[7]);
            *(uint4*)(Vt + ((size_t)(h * 144 + vrow)) * NN + n0) = pk;
        } else {
            #pragma unroll
            for (int nb = 0; nb < 8; ++nb)
                kqs[dsti][nb][h][col] = f2b(scale * acc[nb]);
        }
    }
    __syncthreads();

    // flush Kf/Qf cols 0..79 from staging (coalesced uint4)
    for (int i = t; i < 1280; i += 512) {
        int dsti = i / 640, rem = i - dsti * 640;
        int row = rem / 10, part = rem - row * 10;
        int h = row >> 3, nb = row & 7;
        uint4 val = *(const uint4*)(&kqs[dsti][nb][h][part * 8]);
        ushort* g = (dsti ? Qf : Kf) + ((size_t)h * NN + n0 + nb) * 128 + part * 8;
        *(uint4*)g = val;
    }

    // merged finish: d2 slot channels (cols 80..127), one thread per (h, nb)
    if (t < 64) {
        int h = t >> 3, nb = t & 7, n = n0 + nb;
        float pqx = pqs[nb][0], pqy = pqs[nb][1], pqz = pqs[nb][2];
        float pkx = pos_k[n * 3], pky = pos_k[n * 3 + 1], pkz = pos_k[n * 3 + 2];

        ushort phx = f2b(pqx), phy = f2b(pqy), phz = f2b(pqz);
        float sq = pqx * pqx + pqy * pqy + pqz * pqz;
        ushort sqh = f2b(sq);
        ushort thx = f2b(pkx), thy = f2b(pky), thz = f2b(pkz);
        ushort qhx = f2b(-2.0f * b2f(thx)), qhy = f2b(-2.0f * b2f(thy)), qhz = f2b(-2.0f * b2f(thz));
        float sk = pkx * pkx + pky * pky + pkz * pkz;
        ushort skh = f2b(sk);

        uint4 z4; z4.x = 0; z4.y = 0; z4.z = 0; z4.w = 0;
        uint4 ka0, ka1;
        ka0.x = pu(phx, f2b(pqx - b2f(phx)));
        ka0.y = pu(phx, phy);
        ka0.z = pu(f2b(pqy - b2f(phy)), phy);
        ka0.w = pu(phz, f2b(pqz - b2f(phz)));
        ka1.x = pu(phz, sqh);
        ka1.y = pu(f2b(sq - b2f(sqh)), 0x3F80);
        ka1.z = pu(0x3F80, 0);
        ka1.w = 0;
        uint4 qa0, qa1;
        qa0.x = pu(qhx, qhx);
        qa0.y = pu(f2b(-2.0f * (pkx - b2f(thx))), qhy);
        qa0.z = pu(qhy, f2b(-2.0f * (pky - b2f(thy))));
        qa0.w = pu(qhz, qhz);
        qa1.x = pu(f2b(-2.0f * (pkz - b2f(thz))), 0x3F80);
        qa1.y = pu(0x3F80, skh);
        qa1.z = pu(f2b(sk - b2f(skh)), 0);
        qa1.w = 0;

        ushort* Ko = Kf + ((size_t)h * NN + n) * 128;
        ushort* Qo = Qf + ((size_t)h * NN + n) * 128;
        *(uint4*)(Ko + 80) = z4;  *(uint4*)(Ko + 88) = z4;
        *(uint4*)(Ko + 96) = ka0; *(uint4*)(Ko + 104) = ka1;
        *(uint4*)(Ko + 112) = z4; *(uint4*)(Ko + 120) = z4;
        *(uint4*)(Qo + 80) = z4;  *(uint4*)(Qo + 88) = z4;
        *(uint4*)(Qo + 96) = qa0; *(uint4*)(Qo + 104) = qa1;
        *(uint4*)(Qo + 112) = z4; *(uint4*)(Qo + 120) = z4;
    } else if (t < 128) {
        // Vt const rows 40..47 for this block's 8 nodes
        int idx = t - 64, h = idx >> 3, rw = 40 + (idx & 7);
        uint4 cv;
        if (rw == 40) { cv.x = 0x3F803F80u; cv.y = 0x3F803F80u; cv.z = 0x3F803F80u; cv.w = 0x3F803F80u; }
        else          { cv.x = 0; cv.y = 0; cv.z = 0; cv.w = 0; }
        *(uint4*)(Vt + ((size_t)(h * 144 + rw)) * NN + n0) = cv;
    }
}

// ---------------------------------------------------------------------------
// Kernel B: attention — R19 passing text, verbatim.
// ---------------------------------------------------------------------------
__global__ __launch_bounds__(256, 4) void attn_kernel(
    const ushort* __restrict__ Kf, const ushort* __restrict__ Qf,
    const ushort* __restrict__ Vt, const float* __restrict__ pos_k,
    const float* __restrict__ r0, float* __restrict__ out)
{
    __shared__ __align__(16) char smem[39168];
    const int bid = blockIdx.x;
    const int h = bid & 7;
    const int m0 = (bid >> 3) * 32;
    const int t = threadIdx.x;
    const int lane = t & 63, w = t >> 6;
    const int l15 = lane & 15, lg = lane >> 4;
    const int kh = w >> 1, qh = w & 1;

    const float r0h = r0[h], r0sq = r0h * r0h;
    const ushort* Kg = Kf + (size_t)h * NN * 128;
    const ushort* Vg = Vt + (size_t)h * 144 * NN;

    const ushort* Qp = Qf + ((size_t)h * NN + m0 + qh * 16 + l15) * 128 + lg * 8;
    const s8 qb0 = *(const s8*)(Qp);
    const s8 qb1 = *(const s8*)(Qp + 32);
    const s8 qb2 = *(const s8*)(Qp + 64);
    const s8 qb3 = *(const s8*)(Qp + 96);

    f4 acc[9];
    #pragma unroll
    for (int jb = 0; jb < 9; ++jb) acc[jb] = (f4){0.f, 0.f, 0.f, 0.f};

    uint4 kreg0, kreg1, vreg0, vreg1, vreg2;
    const int kt = t >> 4, kgr = t & 15;
    const int vf = t >> 2, vg = t & 3;
    const int kc = kgr * 8;
    const int vc = vg * 8;
    const int kS = (((kgr & 8) | ((kgr + kt) & 7))) << 4;
    const int kws0 = kt * 256 + kS;
    const int kws1 = kws0 + 4096;
    const int vS = ((vg + (vf >> 1)) & 3) << 4;
    const int vws0 = vf * 64 + vS;
    const int vws1 = vws0 + 4096;
    const int vws2 = vws0 + 8192;

    const int kro = (kh * 16 + l15) * 256;
    const int e0 = ((lg + l15) & 7) << 4;
    const int e1 = ((lg + l15 + 4) & 7) << 4;
    const int vxo = (((kh * 2 + (lg >> 1) + (l15 >> 1)) & 3) << 4) + ((lg & 1) << 3);

#define LOAD_TILE(k0)                                                               \
    kreg0 = *(const uint4*)(Kg + (size_t)((k0) + kt) * 128 + kc);                   \
    kreg1 = *(const uint4*)(Kg + (size_t)((k0) + 16 + kt) * 128 + kc);              \
    vreg0 = *(const uint4*)(Vg + (size_t)vf * NN + (k0) + vc);                      \
    vreg1 = *(const uint4*)(Vg + (size_t)(vf + 64) * NN + (k0) + vc);               \
    if (t < 64) vreg2 = *(const uint4*)(Vg + (size_t)(vf + 128) * NN + (k0) + vc);

#define WRITE_TILE(b)                                                               \
  { char* kb_ = smem + (b) * 17408; char* vb_ = kb_ + 8192;                         \
    *(uint4*)(kb_ + kws0) = kreg0;  *(uint4*)(kb_ + kws1) = kreg1;                  \
    *(uint4*)(vb_ + vws0) = vreg0;  *(uint4*)(vb_ + vws1) = vreg1;                  \
    if (t < 64) *(uint4*)(vb_ + vws2) = vreg2; }

#define COMPUTE_TILE(b)                                                             \
  { const char* kb_ = smem + (b) * 17408; const char* vb_ = kb_ + 8192;             \
    const char* kr = kb_ + kro;                                                     \
    s8 ka0 = *(const s8*)(kr + e0);                                                 \
    s8 ka1 = *(const s8*)(kr + e1);                                                 \
    s8 ka2 = *(const s8*)(kr + 128 + e0);                                           \
    s8 ka3 = *(const s8*)(kr + 128 + e1);                                           \
    f4 z = (f4){0.f, 0.f, 0.f, 0.f};                                                \
    f4 dt = mfma32(ka0, qb0, z);                                                    \
    dt = mfma32(ka1, qb1, dt);                                                      \
    dt = mfma32(ka2, qb2, dt);                                                      \
    f4 dd = mfma32(ka3, qb3, z);                                                    \
    float pv[4], gv[4];                                                             \
    _Pragma("unroll")                                                               \
    for (int r = 0; r < 4; ++r) {                                                   \
      float x = r0sq + dd[r];                                                       \
      float rs = __builtin_amdgcn_rsqf(x);                                          \
      float tt = rs * rs;                                                           \
      float y = dt[r];                                                              \
      float e = fmaf(y, fmaf(0.5f, y, 1.0f), 1.0f);                                 \
      pv[r] = r0sq * tt * e;                                                        \
      gv[r] = pv[r] * rs;                                                           \
    }                                                                               \
    s4 pb = pack4(pv[0], pv[1], pv[2], pv[3]);                                      \
    s4 gb = pack4(gv[0], gv[1], gv[2], gv[3]);                                      \
    const char* vr = vb_ + l15 * 64 + vxo;                                          \
    _Pragma("unroll")                                                               \
    for (int jb = 0; jb < 3; ++jb)                                                  \
      acc[jb] = mfma16(*(const s4*)(vr + jb * 1024), pb, acc[jb]);                  \
    _Pragma("unroll")                                                               \
    for (int jb = 3; jb < 9; ++jb)                                                  \
      acc[jb] = mfma16(*(const s4*)(vr + jb * 1024), gb, acc[jb]);                  \
  }

    LOAD_TILE(0)
    WRITE_TILE(0)
    __syncthreads();
    #pragma unroll 2
    for (int tile = 0; tile < 64; ++tile) {
        int b = tile & 1;
        if (tile < 63) { LOAD_TILE((tile + 1) * 32) }
        COMPUTE_TILE(b)
        __syncthreads();
        if (tile < 63) { WRITE_TILE(b ^ 1) }
        __syncthreads();
    }

    // ---- pair reduction over key-halves (w pairs with w+2, same qh) ----
    float* smemf = (float*)smem;
    float my[36];
    #pragma unroll
    for (int jb = 0; jb < 9; ++jb)
        #pragma unroll
        for (int r = 0; r < 4; ++r)
            my[jb * 4 + r] = acc[jb][r];

    if (w >= 2) {
        float* p = smemf + ((w - 2) * 64 + lane) * 37;
        #pragma unroll
        for (int i = 0; i < 36; ++i) p[i] = my[i];
    }
    __syncthreads();
    if (w < 2) {
        const float* p = smemf + (w * 64 + lane) * 37;
        #pragma unroll
        for (int i = 0; i < 36; ++i) my[i] += p[i];
    }
    __syncthreads();
    if (w < 2) {
        #pragma unroll
        for (int jb = 0; jb < 9; ++jb)
            #pragma unroll
            for (int r = 0; r < 4; ++r)
                smemf[((size_t)w * 144 + jb * 16 + lg * 4 + r) * 17 + l15]
                    = my[jb * 4 + r];
    }
    __syncthreads();

    // ---- epilogue: thread t -> (query q = t&31, task = t>>5 of 5 outputs) ----
    {
        int q = t & 31, task = t >> 5;
        int m = m0 + q, qh2 = q >> 4, ml = q & 15;
        const float* R = smemf + (size_t)qh2 * 144 * 17 + ml;
        float inv = 1.0f / R[40 * 17];
        float pk0 = pos_k[m * 3], pk1 = pos_k[m * 3 + 1], pk2 = pos_k[m * 3 + 2];
        #pragma unroll
        for (int oo = 0; oo < 5; ++oo) {
            int o = task * 5 + oo;
            if (o < 16) {
                int i = o;
                float val = R[i * 17] + pk0 * R[(48 + 3 * i) * 17] + pk1 * R[(49 + 3 * i) * 17]
                          + pk2 * R[(50 + 3 * i) * 17] - R[(96 + i) * 17];
                out[(size_t)m * 128 + h * 16 + i] = val * inv;
            } else {
                int s = o - 16, ip = s / 3, v3 = s - 3 * ip;
                float pkv = (v3 == 0) ? pk0 : ((v3 == 1) ? pk1 : pk2);
                float val = R[(16 + s) * 17] + pkv * R[(112 + ip) * 17] - R[(120 + s) * 17];
                out[(size_t)NN * 128 + (size_t)m * 192 + h * 24 + s] = val * inv;
            }
        }
    }
#undef LOAD_TILE
#undef WRITE_TILE
#undef COMPUTE_TILE
}

extern "C" void kernel_launch(void* const* d_in, const int* in_sizes, int n_in,
                              void* d_out, int out_size, void* d_ws, size_t ws_size,
                              hipStream_t stream) {
    const float* ax       = (const float*)d_in[0];
    const float* vx       = (const float*)d_in[1];
    const float* pos_k    = (const float*)d_in[2];
    const float* pos_q    = (const float*)d_in[3];
    const float* r0       = (const float*)d_in[4];
    const float* W_ak     = (const float*)d_in[5];
    const float* W_vk     = (const float*)d_in[6];
    const float* W_aq     = (const float*)d_in[7];
    const float* W_vq     = (const float*)d_in[8];
    const float* W_aval   = (const float*)d_in[9];
    const float* W_vval   = (const float*)d_in[10];
    const float* W_a2vval = (const float*)d_in[11];
    const float* W_v2aval = (const float*)d_in[12];

    ushort* Kf = (ushort*)d_ws;                        // 8*2048*128 ushort
    ushort* Qf = Kf + (size_t)NH * NN * 128;           // 8*2048*128 ushort
    ushort* Vt = Qf + (size_t)NH * NN * 128;           // 8*144*2048 ushort
    float*  Wtr = (float*)(Vt + (size_t)NH * 144 * NN); // 128*2368 float
    float*  outp = (float*)d_out;

    hipLaunchKernelGGL(wtrans_kernel, dim3((NTASK * 128 + 255) / 256), dim3(256), 0, stream,
                       W_ak, W_vk, W_aq, W_vq, W_aval, W_vval, W_a2vval, W_v2aval, Wtr);
    hipLaunchKernelGGL(proj_kernel, dim3(NN / 8), dim3(512), 0, stream,
                       ax, vx, pos_k, pos_q, Wtr, Kf, Qf, Vt);
    hipLaunchKernelGGL(attn_kernel, dim3(64 * NH), dim3(256), 0, stream,
                       Kf, Qf, Vt, pos_k, r0, outp);
}

// Round 21
// 99.002 us; speedup vs baseline: 1.1318x; 1.1318x over previous
//
#include <hip/hip_runtime.h>

#define NN 2048
#define NH 8

typedef __attribute__((ext_vector_type(4))) short s4;
typedef __attribute__((ext_vector_type(8))) short s8;
typedef __attribute__((ext_vector_type(4))) float f4;

static __device__ __forceinline__ ushort f2b(float x) {
    uint u = __builtin_bit_cast(uint, x);
    uint r = (u + 0x7FFFu + ((u >> 16) & 1u)) >> 16;
    return (ushort)r;
}
static __device__ __forceinline__ float b2f(ushort b) {
    return __builtin_bit_cast(float, ((uint)b) << 16);
}
static __device__ __forceinline__ uint pu(ushort a, ushort b) {
    return (uint)a | ((uint)b << 16);
}
// Pure-C bf16x2 pack (RNE). NO inline asm anywhere (rounds 4-10's NaNs were
// an inline-asm producer -> MFMA hazard lottery; builtin-only is safe).
static __device__ __forceinline__ uint bpack(float lo, float hi) {
    return pu(f2b(lo), f2b(hi));
}
static __device__ __forceinline__ s4 pack4(float a, float b, float c, float d) {
    uint2 w; w.x = bpack(a, b); w.y = bpack(c, d);
    return __builtin_bit_cast(s4, w);
}
static __device__ __forceinline__ f4 mfma32(s8 a, s8 b, f4 c) {
    return __builtin_amdgcn_mfma_f32_16x16x32_bf16(a, b, c, 0, 0, 0);
}
static __device__ __forceinline__ f4 mfma16(s4 a, s4 b, f4 c) {
    const s4 z4s = {0, 0, 0, 0};
    s8 a8 = __builtin_shufflevector(a, z4s, 0, 1, 2, 3, 4, 5, 6, 7);
    s8 b8 = __builtin_shufflevector(b, z4s, 0, 1, 2, 3, 4, 5, 6, 7);
    return __builtin_amdgcn_mfma_f32_16x16x32_bf16(a8, b8, c, 0, 0, 0);
}

// ---------------------------------------------------------------------------
// Kernel A (R19-passing version, verbatim): merged proj+finish+vtrans.
// 256 blocks x 512 threads, 8 nodes/block.
// ---------------------------------------------------------------------------
__global__ __launch_bounds__(512) void proj_kernel(
    const float* __restrict__ ax, const float* __restrict__ vx,
    const float* __restrict__ pos_k, const float* __restrict__ pos_q,
    const float* __restrict__ W_ak, const float* __restrict__ W_vk,
    const float* __restrict__ W_aq, const float* __restrict__ W_vq,
    const float* __restrict__ W_aval, const float* __restrict__ W_vval,
    const float* __restrict__ W_a2vval, const float* __restrict__ W_v2aval,
    ushort* __restrict__ Kf, ushort* __restrict__ Qf, ushort* __restrict__ Vt)
{
    __shared__ float axs[8][128];
    __shared__ float vxs[3][8][64];
    __shared__ float xts[8][64];
    __shared__ float pqs[8][3];
    __shared__ __align__(16) ushort kqs[2][8][8][80];   // [dst][node][head][col]
    const int t  = threadIdx.x;
    const int n0 = blockIdx.x * 8;

    for (int idx = t; idx < 1024; idx += 512)
        axs[idx >> 7][idx & 127] = ax[n0 * 128 + idx];
    for (int idx = t; idx < 1536; idx += 512) {
        int nb = idx / 192, r = idx - nb * 192;
        int j = r / 3, v = r - j * 3;
        vxs[v][nb][j] = vx[n0 * 192 + idx];
    }
    if (t < 24) pqs[t / 3][t % 3] = pos_q[n0 * 3 + t];
    __syncthreads();
    {
        int nb = t >> 6, j = t & 63;
        xts[nb][j] = vxs[0][nb][j] * pqs[nb][0] + vxs[1][nb][j] * pqs[nb][1]
                   + vxs[2][nb][j] * pqs[nb][2];
    }
    __syncthreads();

    #pragma unroll 1
    for (int rr = 0; rr < 5; ++rr) {
        int r = rr * 512 + t;
        if (r >= 2368) continue;
        const float* wrow; int h, v = 0, col = -1, vrow = -1, dsti = 0, srcT = 0, pv = -1;
        float scale = 1.0f;
        if (r < 256)       { int q = r;        h = q >> 5; wrow = W_ak + q * 128; srcT = 0; col = q & 31; dsti = 0; }
        else if (r < 512)  { int q = r - 256;  h = q >> 5; wrow = W_aq + q * 128; srcT = 0; col = q & 31; dsti = 1; scale = 0.1f; }
        else if (r < 896)  { int q = r - 512;  h = q / 48; int s = q - h * 48; v = s % 3; wrow = W_vk + (h * 16 + s / 3) * 64; srcT = 1; col = 32 + s; dsti = 0; }
        else if (r < 1280) { int q = r - 896;  h = q / 48; int s = q - h * 48; v = s % 3; wrow = W_vq + (h * 16 + s / 3) * 64; srcT = 1; col = 32 + s; dsti = 1; scale = 0.1f; }
        else if (r < 1408) { int q = r - 1280; h = q >> 4; wrow = W_aval + q * 128; srcT = 0; vrow = q & 15; }
        else if (r < 1600) { int q = r - 1408; h = q / 24; int s = q - h * 24; v = s % 3; wrow = W_vval + (h * 8 + s / 3) * 64; srcT = 1; vrow = 16 + s; }
        else if (r < 1984) { int q = r - 1600; h = q / 48; int s = q - h * 48; v = s % 3; wrow = W_v2aval + (h * 16 + s / 3) * 64; srcT = 1; vrow = 48 + s; }
        else if (r < 2048) { int q = r - 1984; h = q >> 3; wrow = W_a2vval + q * 128; srcT = 0; vrow = 112 + (q & 7); }
        else if (r < 2176) { int q = r - 2048; h = q >> 4; wrow = W_v2aval + (h * 16 + (q & 15)) * 64; srcT = 2; vrow = 96 + (q & 15); }
        else               { int q = r - 2176; h = q / 24; int s = q - h * 24; int i = s / 3; pv = s % 3; wrow = W_a2vval + (h * 8 + i) * 128; srcT = 0; vrow = 120 + s; }

        float acc[8] = {0.f, 0.f, 0.f, 0.f, 0.f, 0.f, 0.f, 0.f};
        if (srcT == 0) {
            for (int j = 0; j < 128; j += 4) {
                float4 w4 = *(const float4*)(wrow + j);
                #pragma unroll
                for (int nb = 0; nb < 8; ++nb) {
                    float4 x4 = *(const float4*)(&axs[nb][j]);
                    acc[nb] += w4.x * x4.x + w4.y * x4.y + w4.z * x4.z + w4.w * x4.w;
                }
            }
        } else {
            const float* sp = (srcT == 1) ? &vxs[v][0][0] : &xts[0][0];
            for (int j = 0; j < 64; j += 4) {
                float4 w4 = *(const float4*)(wrow + j);
                #pragma unroll
                for (int nb = 0; nb < 8; ++nb) {
                    float4 x4 = *(const float4*)(sp + nb * 64 + j);
                    acc[nb] += w4.x * x4.x + w4.y * x4.y + w4.z * x4.z + w4.w * x4.w;
                }
            }
        }
        if (vrow >= 0) {
            float o[8];
            #pragma unroll
            for (int nb = 0; nb < 8; ++nb)
                o[nb] = acc[nb] * (pv >= 0 ? pqs[nb][pv] : 1.0f);
            uint4 pk;
            pk.x = bpack(o[0], o[1]); pk.y = bpack(o[2], o[3]);
            pk.z = bpack(o[4], o[5]); pk.w = bpack(o[6], o[7]);
            *(uint4*)(Vt + ((size_t)(h * 144 + vrow)) * NN + n0) = pk;
        } else {
            #pragma unroll
            for (int nb = 0; nb < 8; ++nb)
                kqs[dsti][nb][h][col] = f2b(scale * acc[nb]);
        }
    }
    __syncthreads();

    // flush Kf/Qf cols 0..79 from staging (coalesced uint4)
    for (int i = t; i < 1280; i += 512) {
        int dsti = i / 640, rem = i - dsti * 640;
        int row = rem / 10, part = rem - row * 10;
        int h = row >> 3, nb = row & 7;
        uint4 val = *(const uint4*)(&kqs[dsti][nb][h][part * 8]);
        ushort* g = (dsti ? Qf : Kf) + ((size_t)h * NN + n0 + nb) * 128 + part * 8;
        *(uint4*)g = val;
    }

    // merged finish: d2 slot channels (cols 80..127), one thread per (h, nb)
    if (t < 64) {
        int h = t >> 3, nb = t & 7, n = n0 + nb;
        float pqx = pqs[nb][0], pqy = pqs[nb][1], pqz = pqs[nb][2];
        float pkx = pos_k[n * 3], pky = pos_k[n * 3 + 1], pkz = pos_k[n * 3 + 2];

        ushort phx = f2b(pqx), phy = f2b(pqy), phz = f2b(pqz);
        float sq = pqx * pqx + pqy * pqy + pqz * pqz;
        ushort sqh = f2b(sq);
        ushort thx = f2b(pkx), thy = f2b(pky), thz = f2b(pkz);
        ushort qhx = f2b(-2.0f * b2f(thx)), qhy = f2b(-2.0f * b2f(thy)), qhz = f2b(-2.0f * b2f(thz));
        float sk = pkx * pkx + pky * pky + pkz * pkz;
        ushort skh = f2b(sk);

        uint4 z4; z4.x = 0; z4.y = 0; z4.z = 0; z4.w = 0;
        uint4 ka0, ka1;
        ka0.x = pu(phx, f2b(pqx - b2f(phx)));
        ka0.y = pu(phx, phy);
        ka0.z = pu(f2b(pqy - b2f(phy)), phy);
        ka0.w = pu(phz, f2b(pqz - b2f(phz)));
        ka1.x = pu(phz, sqh);
        ka1.y = pu(f2b(sq - b2f(sqh)), 0x3F80);
        ka1.z = pu(0x3F80, 0);
        ka1.w = 0;
        uint4 qa0, qa1;
        qa0.x = pu(qhx, qhx);
        qa0.y = pu(f2b(-2.0f * (pkx - b2f(thx))), qhy);
        qa0.z = pu(qhy, f2b(-2.0f * (pky - b2f(thy))));
        qa0.w = pu(qhz, qhz);
        qa1.x = pu(f2b(-2.0f * (pkz - b2f(thz))), 0x3F80);
        qa1.y = pu(0x3F80, skh);
        qa1.z = pu(f2b(sk - b2f(skh)), 0);
        qa1.w = 0;

        ushort* Ko = Kf + ((size_t)h * NN + n) * 128;
        ushort* Qo = Qf + ((size_t)h * NN + n) * 128;
        *(uint4*)(Ko + 80) = z4;  *(uint4*)(Ko + 88) = z4;
        *(uint4*)(Ko + 96) = ka0; *(uint4*)(Ko + 104) = ka1;
        *(uint4*)(Ko + 112) = z4; *(uint4*)(Ko + 120) = z4;
        *(uint4*)(Qo + 80) = z4;  *(uint4*)(Qo + 88) = z4;
        *(uint4*)(Qo + 96) = qa0; *(uint4*)(Qo + 104) = qa1;
        *(uint4*)(Qo + 112) = z4; *(uint4*)(Qo + 120) = z4;
    } else if (t < 128) {
        // Vt const rows 40..47 for this block's 8 nodes
        int idx = t - 64, h = idx >> 3, rw = 40 + (idx & 7);
        uint4 cv;
        if (rw == 40) { cv.x = 0x3F803F80u; cv.y = 0x3F803F80u; cv.z = 0x3F803F80u; cv.w = 0x3F803F80u; }
        else          { cv.x = 0; cv.y = 0; cv.z = 0; cv.w = 0; }
        *(uint4*)(Vt + ((size_t)(h * 144 + rw)) * NN + n0) = cv;
    }
}

// ---------------------------------------------------------------------------
// Kernel B: attention. Grid 512 = 64 m-tiles x 8 heads; block 512 threads =
// TWO independent 4-wave groups; group wg processes key-half wg*1024..+1023
// in its own 39168-B LDS region (R19 hot loop verbatim, t -> tl = t&255,
// 32 tiles, k0 += wg*1024). 16 waves/CU (was 8). Cross-group reduction stage
// added; epilogue spread over 512 threads.
// ---------------------------------------------------------------------------
__global__ __launch_bounds__(512, 2) void attn_kernel(
    const ushort* __restrict__ Kf, const ushort* __restrict__ Qf,
    const ushort* __restrict__ Vt, const float* __restrict__ pos_k,
    const float* __restrict__ r0, float* __restrict__ out)
{
    __shared__ __align__(16) char smem[78336];
    const int bid = blockIdx.x;
    const int h = bid & 7;
    const int m0 = (bid >> 3) * 32;
    const int t = threadIdx.x;
    const int wg = t >> 8;           // key-half group (0/1)
    const int tl = t & 255;          // id within group
    const int lane = tl & 63, w = tl >> 6;   // wave in group (0..3)
    const int l15 = lane & 15, lg = lane >> 4;
    const int kh = w >> 1, qh = w & 1;

    const float r0h = r0[h], r0sq = r0h * r0h;
    const ushort* Kg = Kf + (size_t)h * NN * 128;
    const ushort* Vg = Vt + (size_t)h * 144 * NN;

    const ushort* Qp = Qf + ((size_t)h * NN + m0 + qh * 16 + l15) * 128 + lg * 8;
    const s8 qb0 = *(const s8*)(Qp);
    const s8 qb1 = *(const s8*)(Qp + 32);
    const s8 qb2 = *(const s8*)(Qp + 64);
    const s8 qb3 = *(const s8*)(Qp + 96);

    f4 acc[9];
    #pragma unroll
    for (int jb = 0; jb < 9; ++jb) acc[jb] = (f4){0.f, 0.f, 0.f, 0.f};

    char* gbase = smem + wg * 39168;
    const int kbase0 = wg * 1024;    // this group's first key

    uint4 kreg0, kreg1, vreg0, vreg1, vreg2;
    const int kt = tl >> 4, kgr = tl & 15;
    const int vf = tl >> 2, vg = tl & 3;
    const int kc = kgr * 8;
    const int vc = vg * 8;
    const int kS = (((kgr & 8) | ((kgr + kt) & 7))) << 4;
    const int kws0 = kt * 256 + kS;
    const int kws1 = kws0 + 4096;
    const int vS = ((vg + (vf >> 1)) & 3) << 4;
    const int vws0 = vf * 64 + vS;
    const int vws1 = vws0 + 4096;
    const int vws2 = vws0 + 8192;

    const int kro = (kh * 16 + l15) * 256;
    const int e0 = ((lg + l15) & 7) << 4;
    const int e1 = ((lg + l15 + 4) & 7) << 4;
    const int vxo = (((kh * 2 + (lg >> 1) + (l15 >> 1)) & 3) << 4) + ((lg & 1) << 3);

#define LOAD_TILE(k0)                                                               \
    kreg0 = *(const uint4*)(Kg + (size_t)((k0) + kt) * 128 + kc);                   \
    kreg1 = *(const uint4*)(Kg + (size_t)((k0) + 16 + kt) * 128 + kc);              \
    vreg0 = *(const uint4*)(Vg + (size_t)vf * NN + (k0) + vc);                      \
    vreg1 = *(const uint4*)(Vg + (size_t)(vf + 64) * NN + (k0) + vc);               \
    if (tl < 64) vreg2 = *(const uint4*)(Vg + (size_t)(vf + 128) * NN + (k0) + vc);

#define WRITE_TILE(b)                                                               \
  { char* kb_ = gbase + (b) * 17408; char* vb_ = kb_ + 8192;                        \
    *(uint4*)(kb_ + kws0) = kreg0;  *(uint4*)(kb_ + kws1) = kreg1;                  \
    *(uint4*)(vb_ + vws0) = vreg0;  *(uint4*)(vb_ + vws1) = vreg1;                  \
    if (tl < 64) *(uint4*)(vb_ + vws2) = vreg2; }

#define COMPUTE_TILE(b)                                                             \
  { const char* kb_ = gbase + (b) * 17408; const char* vb_ = kb_ + 8192;            \
    const char* kr = kb_ + kro;                                                     \
    s8 ka0 = *(const s8*)(kr + e0);                                                 \
    s8 ka1 = *(const s8*)(kr + e1);                                                 \
    s8 ka2 = *(const s8*)(kr + 128 + e0);                                           \
    s8 ka3 = *(const s8*)(kr + 128 + e1);                                           \
    f4 z = (f4){0.f, 0.f, 0.f, 0.f};                                                \
    f4 dt = mfma32(ka0, qb0, z);                                                    \
    dt = mfma32(ka1, qb1, dt);                                                      \
    dt = mfma32(ka2, qb2, dt);                                                      \
    f4 dd = mfma32(ka3, qb3, z);                                                    \
    float pv[4], gv[4];                                                             \
    _Pragma("unroll")                                                               \
    for (int r = 0; r < 4; ++r) {                                                   \
      float x = r0sq + dd[r];                                                       \
      float rs = __builtin_amdgcn_rsqf(x);                                          \
      float tt = rs * rs;                                                           \
      float y = dt[r];                                                              \
      float e = fmaf(y, fmaf(0.5f, y, 1.0f), 1.0f);                                 \
      pv[r] = r0sq * tt * e;                                                        \
      gv[r] = pv[r] * rs;                                                           \
    }                                                                               \
    s4 pb = pack4(pv[0], pv[1], pv[2], pv[3]);                                      \
    s4 gb = pack4(gv[0], gv[1], gv[2], gv[3]);                                      \
    const char* vr = vb_ + l15 * 64 + vxo;                                          \
    _Pragma("unroll")                                                               \
    for (int jb = 0; jb < 3; ++jb)                                                  \
      acc[jb] = mfma16(*(const s4*)(vr + jb * 1024), pb, acc[jb]);                  \
    _Pragma("unroll")                                                               \
    for (int jb = 3; jb < 9; ++jb)                                                  \
      acc[jb] = mfma16(*(const s4*)(vr + jb * 1024), gb, acc[jb]);                  \
  }

    LOAD_TILE(kbase0)
    WRITE_TILE(0)
    __syncthreads();
    #pragma unroll 2
    for (int tile = 0; tile < 32; ++tile) {
        int b = tile & 1;
        if (tile < 31) { LOAD_TILE(kbase0 + (tile + 1) * 32) }
        COMPUTE_TILE(b)
        __syncthreads();
        if (tile < 31) { WRITE_TILE(b ^ 1) }
        __syncthreads();
    }

    // ---- reduction: intra-group pair (kh), then cross-group (wg), scatter ----
    float* smemf = (float*)smem;
    float my[36];
    #pragma unroll
    for (int jb = 0; jb < 9; ++jb)
        #pragma unroll
        for (int r = 0; r < 4; ++r)
            my[jb * 4 + r] = acc[jb][r];

    if (w >= 2) {
        float* p = smemf + wg * 4736 + ((w - 2) * 64 + lane) * 37;
        #pragma unroll
        for (int i = 0; i < 36; ++i) p[i] = my[i];
    }
    __syncthreads();
    if (w < 2) {
        const float* p = smemf + wg * 4736 + (w * 64 + lane) * 37;
        #pragma unroll
        for (int i = 0; i < 36; ++i) my[i] += p[i];
    }
    __syncthreads();
    if (wg == 1 && w < 2) {
        float* p = smemf + 9472 + (w * 64 + lane) * 37;
        #pragma unroll
        for (int i = 0; i < 36; ++i) p[i] = my[i];
    }
    __syncthreads();
    if (wg == 0 && w < 2) {
        const float* p = smemf + 9472 + (w * 64 + lane) * 37;
        #pragma unroll
        for (int i = 0; i < 36; ++i) my[i] += p[i];
        #pragma unroll
        for (int jb = 0; jb < 9; ++jb)
            #pragma unroll
            for (int r = 0; r < 4; ++r)
                smemf[14208 + ((size_t)w * 144 + jb * 16 + lg * 4 + r) * 17 + l15]
                    = my[jb * 4 + r];
    }
    __syncthreads();

    // ---- epilogue: 512 threads; thread -> (q = t&31, task = t>>5 of 3 outs) ----
    {
        int q = t & 31, task = t >> 5;       // task 0..15
        int m = m0 + q, qh2 = q >> 4, ml = q & 15;
        const float* R = smemf + 14208 + (size_t)qh2 * 144 * 17 + ml;
        float inv = 1.0f / R[40 * 17];
        float pk0 = pos_k[m * 3], pk1 = pos_k[m * 3 + 1], pk2 = pos_k[m * 3 + 2];
        #pragma unroll
        for (int oo = 0; oo < 3; ++oo) {
            int o = task * 3 + oo;
            if (o >= 40) continue;
            if (o < 16) {
                int i = o;
                float val = R[i * 17] + pk0 * R[(48 + 3 * i) * 17] + pk1 * R[(49 + 3 * i) * 17]
                          + pk2 * R[(50 + 3 * i) * 17] - R[(96 + i) * 17];
                out[(size_t)m * 128 + h * 16 + i] = val * inv;
            } else {
                int s = o - 16, ip = s / 3, v3 = s - 3 * ip;
                float pkv = (v3 == 0) ? pk0 : ((v3 == 1) ? pk1 : pk2);
                float val = R[(16 + s) * 17] + pkv * R[(112 + ip) * 17] - R[(120 + s) * 17];
                out[(size_t)NN * 128 + (size_t)m * 192 + h * 24 + s] = val * inv;
            }
        }
    }
#undef LOAD_TILE
#undef WRITE_TILE
#undef COMPUTE_TILE
}

extern "C" void kernel_launch(void* const* d_in, const int* in_sizes, int n_in,
                              void* d_out, int out_size, void* d_ws, size_t ws_size,
                              hipStream_t stream) {
    const float* ax       = (const float*)d_in[0];
    const float* vx       = (const float*)d_in[1];
    const float* pos_k    = (const float*)d_in[2];
    const float* pos_q    = (const float*)d_in[3];
    const float* r0       = (const float*)d_in[4];
    const float* W_ak     = (const float*)d_in[5];
    const float* W_vk     = (const float*)d_in[6];
    const float* W_aq     = (const float*)d_in[7];
    const float* W_vq     = (const float*)d_in[8];
    const float* W_aval   = (const float*)d_in[9];
    const float* W_vval   = (const float*)d_in[10];
    const float* W_a2vval = (const float*)d_in[11];
    const float* W_v2aval = (const float*)d_in[12];

    ushort* Kf = (ushort*)d_ws;                        // 8*2048*128
    ushort* Qf = Kf + (size_t)NH * NN * 128;           // 8*2048*128
    ushort* Vt = Qf + (size_t)NH * NN * 128;           // 8*144*2048
    float*  outp = (float*)d_out;

    hipLaunchKernelGGL(proj_kernel, dim3(NN / 8), dim3(512), 0, stream,
                       ax, vx, pos_k, pos_q, W_ak, W_vk, W_aq, W_vq,
                       W_aval, W_vval, W_a2vval, W_v2aval, Kf, Qf, Vt);
    hipLaunchKernelGGL(attn_kernel, dim3(64 * NH), dim3(512), 0, stream,
                       Kf, Qf, Vt, pos_k, r0, outp);
}

// Round 22
// 96.676 us; speedup vs baseline: 1.1591x; 1.0241x over previous
//
#include <hip/hip_runtime.h>

#define NN 2048
#define NH 8

typedef __attribute__((ext_vector_type(4))) short s4;
typedef __attribute__((ext_vector_type(8))) short s8;
typedef __attribute__((ext_vector_type(4))) float f4;

static __device__ __forceinline__ ushort f2b(float x) {
    uint u = __builtin_bit_cast(uint, x);
    uint r = (u + 0x7FFFu + ((u >> 16) & 1u)) >> 16;
    return (ushort)r;
}
static __device__ __forceinline__ float b2f(ushort b) {
    return __builtin_bit_cast(float, ((uint)b) << 16);
}
static __device__ __forceinline__ uint pu(ushort a, ushort b) {
    return (uint)a | ((uint)b << 16);
}
// Pure-C bf16x2 pack (RNE). NO inline asm anywhere (rounds 4-10's NaNs were
// an inline-asm producer -> MFMA hazard lottery; builtin-only is safe).
static __device__ __forceinline__ uint bpack(float lo, float hi) {
    return pu(f2b(lo), f2b(hi));
}
static __device__ __forceinline__ s4 pack4(float a, float b, float c, float d) {
    uint2 w; w.x = bpack(a, b); w.y = bpack(c, d);
    return __builtin_bit_cast(s4, w);
}
static __device__ __forceinline__ f4 mfma32(s8 a, s8 b, f4 c) {
    return __builtin_amdgcn_mfma_f32_16x16x32_bf16(a, b, c, 0, 0, 0);
}
static __device__ __forceinline__ f4 mfma16(s4 a, s4 b, f4 c) {
    const s4 z4s = {0, 0, 0, 0};
    s8 a8 = __builtin_shufflevector(a, z4s, 0, 1, 2, 3, 4, 5, 6, 7);
    s8 b8 = __builtin_shufflevector(b, z4s, 0, 1, 2, 3, 4, 5, 6, 7);
    return __builtin_amdgcn_mfma_f32_16x16x32_bf16(a8, b8, c, 0, 0, 0);
}

// ---------------------------------------------------------------------------
// Kernel A: merged proj+finish+vtrans (R19 structure). ONLY change: 1024
// threads/block (was 512) -> 16 waves/CU for latency hiding; rr loop 5->3;
// xts section guarded to its original 512-thread mapping.
// ---------------------------------------------------------------------------
__global__ __launch_bounds__(1024) void proj_kernel(
    const float* __restrict__ ax, const float* __restrict__ vx,
    const float* __restrict__ pos_k, const float* __restrict__ pos_q,
    const float* __restrict__ W_ak, const float* __restrict__ W_vk,
    const float* __restrict__ W_aq, const float* __restrict__ W_vq,
    const float* __restrict__ W_aval, const float* __restrict__ W_vval,
    const float* __restrict__ W_a2vval, const float* __restrict__ W_v2aval,
    ushort* __restrict__ Kf, ushort* __restrict__ Qf, ushort* __restrict__ Vt)
{
    __shared__ float axs[8][128];
    __shared__ float vxs[3][8][64];
    __shared__ float xts[8][64];
    __shared__ float pqs[8][3];
    __shared__ __align__(16) ushort kqs[2][8][8][80];   // [dst][node][head][col]
    const int t  = threadIdx.x;
    const int n0 = blockIdx.x * 8;

    if (t < 1024)
        axs[t >> 7][t & 127] = ax[n0 * 128 + t];
    for (int idx = t; idx < 1536; idx += 1024) {
        int nb = idx / 192, r = idx - nb * 192;
        int j = r / 3, v = r - j * 3;
        vxs[v][nb][j] = vx[n0 * 192 + idx];
    }
    if (t < 24) pqs[t / 3][t % 3] = pos_q[n0 * 3 + t];
    __syncthreads();
    if (t < 512) {
        int nb = t >> 6, j = t & 63;
        xts[nb][j] = vxs[0][nb][j] * pqs[nb][0] + vxs[1][nb][j] * pqs[nb][1]
                   + vxs[2][nb][j] * pqs[nb][2];
    }
    __syncthreads();

    #pragma unroll 1
    for (int rr = 0; rr < 3; ++rr) {
        int r = rr * 1024 + t;
        if (r >= 2368) continue;
        const float* wrow; int h, v = 0, col = -1, vrow = -1, dsti = 0, srcT = 0, pv = -1;
        float scale = 1.0f;
        if (r < 256)       { int q = r;        h = q >> 5; wrow = W_ak + q * 128; srcT = 0; col = q & 31; dsti = 0; }
        else if (r < 512)  { int q = r - 256;  h = q >> 5; wrow = W_aq + q * 128; srcT = 0; col = q & 31; dsti = 1; scale = 0.1f; }
        else if (r < 896)  { int q = r - 512;  h = q / 48; int s = q - h * 48; v = s % 3; wrow = W_vk + (h * 16 + s / 3) * 64; srcT = 1; col = 32 + s; dsti = 0; }
        else if (r < 1280) { int q = r - 896;  h = q / 48; int s = q - h * 48; v = s % 3; wrow = W_vq + (h * 16 + s / 3) * 64; srcT = 1; col = 32 + s; dsti = 1; scale = 0.1f; }
        else if (r < 1408) { int q = r - 1280; h = q >> 4; wrow = W_aval + q * 128; srcT = 0; vrow = q & 15; }
        else if (r < 1600) { int q = r - 1408; h = q / 24; int s = q - h * 24; v = s % 3; wrow = W_vval + (h * 8 + s / 3) * 64; srcT = 1; vrow = 16 + s; }
        else if (r < 1984) { int q = r - 1600; h = q / 48; int s = q - h * 48; v = s % 3; wrow = W_v2aval + (h * 16 + s / 3) * 64; srcT = 1; vrow = 48 + s; }
        else if (r < 2048) { int q = r - 1984; h = q >> 3; wrow = W_a2vval + q * 128; srcT = 0; vrow = 112 + (q & 7); }
        else if (r < 2176) { int q = r - 2048; h = q >> 4; wrow = W_v2aval + (h * 16 + (q & 15)) * 64; srcT = 2; vrow = 96 + (q & 15); }
        else               { int q = r - 2176; h = q / 24; int s = q - h * 24; int i = s / 3; pv = s % 3; wrow = W_a2vval + (h * 8 + i) * 128; srcT = 0; vrow = 120 + s; }

        float acc[8] = {0.f, 0.f, 0.f, 0.f, 0.f, 0.f, 0.f, 0.f};
        if (srcT == 0) {
            for (int j = 0; j < 128; j += 4) {
                float4 w4 = *(const float4*)(wrow + j);
                #pragma unroll
                for (int nb = 0; nb < 8; ++nb) {
                    float4 x4 = *(const float4*)(&axs[nb][j]);
                    acc[nb] += w4.x * x4.x + w4.y * x4.y + w4.z * x4.z + w4.w * x4.w;
                }
            }
        } else {
            const float* sp = (srcT == 1) ? &vxs[v][0][0] : &xts[0][0];
            for (int j = 0; j < 64; j += 4) {
                float4 w4 = *(const float4*)(wrow + j);
                #pragma unroll
                for (int nb = 0; nb < 8; ++nb) {
                    float4 x4 = *(const float4*)(sp + nb * 64 + j);
                    acc[nb] += w4.x * x4.x + w4.y * x4.y + w4.z * x4.z + w4.w * x4.w;
                }
            }
        }
        if (vrow >= 0) {
            float o[8];
            #pragma unroll
            for (int nb = 0; nb < 8; ++nb)
                o[nb] = acc[nb] * (pv >= 0 ? pqs[nb][pv] : 1.0f);
            uint4 pk;
            pk.x = bpack(o[0], o[1]); pk.y = bpack(o[2], o[3]);
            pk.z = bpack(o[4], o[5]); pk.w = bpack(o[6], o[7]);
            *(uint4*)(Vt + ((size_t)(h * 144 + vrow)) * NN + n0) = pk;
        } else {
            #pragma unroll
            for (int nb = 0; nb < 8; ++nb)
                kqs[dsti][nb][h][col] = f2b(scale * acc[nb]);
        }
    }
    __syncthreads();

    // flush Kf/Qf cols 0..79 from staging (coalesced uint4)
    for (int i = t; i < 1280; i += 1024) {
        int dsti = i / 640, rem = i - dsti * 640;
        int row = rem / 10, part = rem - row * 10;
        int h = row >> 3, nb = row & 7;
        uint4 val = *(const uint4*)(&kqs[dsti][nb][h][part * 8]);
        ushort* g = (dsti ? Qf : Kf) + ((size_t)h * NN + n0 + nb) * 128 + part * 8;
        *(uint4*)g = val;
    }

    // merged finish: d2 slot channels (cols 80..127), one thread per (h, nb)
    if (t < 64) {
        int h = t >> 3, nb = t & 7, n = n0 + nb;
        float pqx = pqs[nb][0], pqy = pqs[nb][1], pqz = pqs[nb][2];
        float pkx = pos_k[n * 3], pky = pos_k[n * 3 + 1], pkz = pos_k[n * 3 + 2];

        ushort phx = f2b(pqx), phy = f2b(pqy), phz = f2b(pqz);
        float sq = pqx * pqx + pqy * pqy + pqz * pqz;
        ushort sqh = f2b(sq);
        ushort thx = f2b(pkx), thy = f2b(pky), thz = f2b(pkz);
        ushort qhx = f2b(-2.0f * b2f(thx)), qhy = f2b(-2.0f * b2f(thy)), qhz = f2b(-2.0f * b2f(thz));
        float sk = pkx * pkx + pky * pky + pkz * pkz;
        ushort skh = f2b(sk);

        uint4 z4; z4.x = 0; z4.y = 0; z4.z = 0; z4.w = 0;
        uint4 ka0, ka1;
        ka0.x = pu(phx, f2b(pqx - b2f(phx)));
        ka0.y = pu(phx, phy);
        ka0.z = pu(f2b(pqy - b2f(phy)), phy);
        ka0.w = pu(phz, f2b(pqz - b2f(phz)));
        ka1.x = pu(phz, sqh);
        ka1.y = pu(f2b(sq - b2f(sqh)), 0x3F80);
        ka1.z = pu(0x3F80, 0);
        ka1.w = 0;
        uint4 qa0, qa1;
        qa0.x = pu(qhx, qhx);
        qa0.y = pu(f2b(-2.0f * (pkx - b2f(thx))), qhy);
        qa0.z = pu(qhy, f2b(-2.0f * (pky - b2f(thy))));
        qa0.w = pu(qhz, qhz);
        qa1.x = pu(f2b(-2.0f * (pkz - b2f(thz))), 0x3F80);
        qa1.y = pu(0x3F80, skh);
        qa1.z = pu(f2b(sk - b2f(skh)), 0);
        qa1.w = 0;

        ushort* Ko = Kf + ((size_t)h * NN + n) * 128;
        ushort* Qo = Qf + ((size_t)h * NN + n) * 128;
        *(uint4*)(Ko + 80) = z4;  *(uint4*)(Ko + 88) = z4;
        *(uint4*)(Ko + 96) = ka0; *(uint4*)(Ko + 104) = ka1;
        *(uint4*)(Ko + 112) = z4; *(uint4*)(Ko + 120) = z4;
        *(uint4*)(Qo + 80) = z4;  *(uint4*)(Qo + 88) = z4;
        *(uint4*)(Qo + 96) = qa0; *(uint4*)(Qo + 104) = qa1;
        *(uint4*)(Qo + 112) = z4; *(uint4*)(Qo + 120) = z4;
    } else if (t >= 64 && t < 128) {
        // Vt const rows 40..47 for this block's 8 nodes
        int idx = t - 64, h = idx >> 3, rw = 40 + (idx & 7);
        uint4 cv;
        if (rw == 40) { cv.x = 0x3F803F80u; cv.y = 0x3F803F80u; cv.z = 0x3F803F80u; cv.w = 0x3F803F80u; }
        else          { cv.x = 0; cv.y = 0; cv.z = 0; cv.w = 0; }
        *(uint4*)(Vt + ((size_t)(h * 144 + rw)) * NN + n0) = cv;
    }
}

// ---------------------------------------------------------------------------
// Kernel B (R21-passing text, verbatim): attention. Grid 512; block 512 =
// two independent 4-wave groups on separate key-halves / LDS regions.
// ---------------------------------------------------------------------------
__global__ __launch_bounds__(512, 2) void attn_kernel(
    const ushort* __restrict__ Kf, const ushort* __restrict__ Qf,
    const ushort* __restrict__ Vt, const float* __restrict__ pos_k,
    const float* __restrict__ r0, float* __restrict__ out)
{
    __shared__ __align__(16) char smem[78336];
    const int bid = blockIdx.x;
    const int h = bid & 7;
    const int m0 = (bid >> 3) * 32;
    const int t = threadIdx.x;
    const int wg = t >> 8;           // key-half group (0/1)
    const int tl = t & 255;          // id within group
    const int lane = tl & 63, w = tl >> 6;   // wave in group (0..3)
    const int l15 = lane & 15, lg = lane >> 4;
    const int kh = w >> 1, qh = w & 1;

    const float r0h = r0[h], r0sq = r0h * r0h;
    const ushort* Kg = Kf + (size_t)h * NN * 128;
    const ushort* Vg = Vt + (size_t)h * 144 * NN;

    const ushort* Qp = Qf + ((size_t)h * NN + m0 + qh * 16 + l15) * 128 + lg * 8;
    const s8 qb0 = *(const s8*)(Qp);
    const s8 qb1 = *(const s8*)(Qp + 32);
    const s8 qb2 = *(const s8*)(Qp + 64);
    const s8 qb3 = *(const s8*)(Qp + 96);

    f4 acc[9];
    #pragma unroll
    for (int jb = 0; jb < 9; ++jb) acc[jb] = (f4){0.f, 0.f, 0.f, 0.f};

    char* gbase = smem + wg * 39168;
    const int kbase0 = wg * 1024;    // this group's first key

    uint4 kreg0, kreg1, vreg0, vreg1, vreg2;
    const int kt = tl >> 4, kgr = tl & 15;
    const int vf = tl >> 2, vg = tl & 3;
    const int kc = kgr * 8;
    const int vc = vg * 8;
    const int kS = (((kgr & 8) | ((kgr + kt) & 7))) << 4;
    const int kws0 = kt * 256 + kS;
    const int kws1 = kws0 + 4096;
    const int vS = ((vg + (vf >> 1)) & 3) << 4;
    const int vws0 = vf * 64 + vS;
    const int vws1 = vws0 + 4096;
    const int vws2 = vws0 + 8192;

    const int kro = (kh * 16 + l15) * 256;
    const int e0 = ((lg + l15) & 7) << 4;
    const int e1 = ((lg + l15 + 4) & 7) << 4;
    const int vxo = (((kh * 2 + (lg >> 1) + (l15 >> 1)) & 3) << 4) + ((lg & 1) << 3);

#define LOAD_TILE(k0)                                                               \
    kreg0 = *(const uint4*)(Kg + (size_t)((k0) + kt) * 128 + kc);                   \
    kreg1 = *(const uint4*)(Kg + (size_t)((k0) + 16 + kt) * 128 + kc);              \
    vreg0 = *(const uint4*)(Vg + (size_t)vf * NN + (k0) + vc);                      \
    vreg1 = *(const uint4*)(Vg + (size_t)(vf + 64) * NN + (k0) + vc);               \
    if (tl < 64) vreg2 = *(const uint4*)(Vg + (size_t)(vf + 128) * NN + (k0) + vc);

#define WRITE_TILE(b)                                                               \
  { char* kb_ = gbase + (b) * 17408; char* vb_ = kb_ + 8192;                        \
    *(uint4*)(kb_ + kws0) = kreg0;  *(uint4*)(kb_ + kws1) = kreg1;                  \
    *(uint4*)(vb_ + vws0) = vreg0;  *(uint4*)(vb_ + vws1) = vreg1;                  \
    if (tl < 64) *(uint4*)(vb_ + vws2) = vreg2; }

#define COMPUTE_TILE(b)                                                             \
  { const char* kb_ = gbase + (b) * 17408; const char* vb_ = kb_ + 8192;            \
    const char* kr = kb_ + kro;                                                     \
    s8 ka0 = *(const s8*)(kr + e0);                                                 \
    s8 ka1 = *(const s8*)(kr + e1);                                                 \
    s8 ka2 = *(const s8*)(kr + 128 + e0);                                           \
    s8 ka3 = *(const s8*)(kr + 128 + e1);                                           \
    f4 z = (f4){0.f, 0.f, 0.f, 0.f};                                                \
    f4 dt = mfma32(ka0, qb0, z);                                                    \
    dt = mfma32(ka1, qb1, dt);                                                      \
    dt = mfma32(ka2, qb2, dt);                                                      \
    f4 dd = mfma32(ka3, qb3, z);                                                    \
    float pv[4], gv[4];                                                             \
    _Pragma("unroll")                                                               \
    for (int r = 0; r < 4; ++r) {                                                   \
      float x = r0sq + dd[r];                                                       \
      float rs = __builtin_amdgcn_rsqf(x);                                          \
      float tt = rs * rs;                                                           \
      float y = dt[r];                                                              \
      float e = fmaf(y, fmaf(0.5f, y, 1.0f), 1.0f);                                 \
      pv[r] = r0sq * tt * e;                                                        \
      gv[r] = pv[r] * rs;                                                           \
    }                                                                               \
    s4 pb = pack4(pv[0], pv[1], pv[2], pv[3]);                                      \
    s4 gb = pack4(gv[0], gv[1], gv[2], gv[3]);                                      \
    const char* vr = vb_ + l15 * 64 + vxo;                                          \
    _Pragma("unroll")                                                               \
    for (int jb = 0; jb < 3; ++jb)                                                  \
      acc[jb] = mfma16(*(const s4*)(vr + jb * 1024), pb, acc[jb]);                  \
    _Pragma("unroll")                                                               \
    for (int jb = 3; jb < 9; ++jb)                                                  \
      acc[jb] = mfma16(*(const s4*)(vr + jb * 1024), gb, acc[jb]);                  \
  }

    LOAD_TILE(kbase0)
    WRITE_TILE(0)
    __syncthreads();
    #pragma unroll 2
    for (int tile = 0; tile < 32; ++tile) {
        int b = tile & 1;
        if (tile < 31) { LOAD_TILE(kbase0 + (tile + 1) * 32) }
        COMPUTE_TILE(b)
        __syncthreads();
        if (tile < 31) { WRITE_TILE(b ^ 1) }
        __syncthreads();
    }

    // ---- reduction: intra-group pair (kh), then cross-group (wg), scatter ----
    float* smemf = (float*)smem;
    float my[36];
    #pragma unroll
    for (int jb = 0; jb < 9; ++jb)
        #pragma unroll
        for (int r = 0; r < 4; ++r)
            my[jb * 4 + r] = acc[jb][r];

    if (w >= 2) {
        float* p = smemf + wg * 4736 + ((w - 2) * 64 + lane) * 37;
        #pragma unroll
        for (int i = 0; i < 36; ++i) p[i] = my[i];
    }
    __syncthreads();
    if (w < 2) {
        const float* p = smemf + wg * 4736 + (w * 64 + lane) * 37;
        #pragma unroll
        for (int i = 0; i < 36; ++i) my[i] += p[i];
    }
    __syncthreads();
    if (wg == 1 && w < 2) {
        float* p = smemf + 9472 + (w * 64 + lane) * 37;
        #pragma unroll
        for (int i = 0; i < 36; ++i) p[i] = my[i];
    }
    __syncthreads();
    if (wg == 0 && w < 2) {
        const float* p = smemf + 9472 + (w * 64 + lane) * 37;
        #pragma unroll
        for (int i = 0; i < 36; ++i) my[i] += p[i];
        #pragma unroll
        for (int jb = 0; jb < 9; ++jb)
            #pragma unroll
            for (int r = 0; r < 4; ++r)
                smemf[14208 + ((size_t)w * 144 + jb * 16 + lg * 4 + r) * 17 + l15]
                    = my[jb * 4 + r];
    }
    __syncthreads();

    // ---- epilogue: 512 threads; thread -> (q = t&31, task = t>>5 of 3 outs) ----
    {
        int q = t & 31, task = t >> 5;       // task 0..15
        int m = m0 + q, qh2 = q >> 4, ml = q & 15;
        const float* R = smemf + 14208 + (size_t)qh2 * 144 * 17 + ml;
        float inv = 1.0f / R[40 * 17];
        float pk0 = pos_k[m * 3], pk1 = pos_k[m * 3 + 1], pk2 = pos_k[m * 3 + 2];
        #pragma unroll
        for (int oo = 0; oo < 3; ++oo) {
            int o = task * 3 + oo;
            if (o >= 40) continue;
            if (o < 16) {
                int i = o;
                float val = R[i * 17] + pk0 * R[(48 + 3 * i) * 17] + pk1 * R[(49 + 3 * i) * 17]
                          + pk2 * R[(50 + 3 * i) * 17] - R[(96 + i) * 17];
                out[(size_t)m * 128 + h * 16 + i] = val * inv;
            } else {
                int s = o - 16, ip = s / 3, v3 = s - 3 * ip;
                float pkv = (v3 == 0) ? pk0 : ((v3 == 1) ? pk1 : pk2);
                float val = R[(16 + s) * 17] + pkv * R[(112 + ip) * 17] - R[(120 + s) * 17];
                out[(size_t)NN * 128 + (size_t)m * 192 + h * 24 + s] = val * inv;
            }
        }
    }
#undef LOAD_TILE
#undef WRITE_TILE
#undef COMPUTE_TILE
}

extern "C" void kernel_launch(void* const* d_in, const int* in_sizes, int n_in,
                              void* d_out, int out_size, void* d_ws, size_t ws_size,
                              hipStream_t stream) {
    const float* ax       = (const float*)d_in[0];
    const float* vx       = (const float*)d_in[1];
    const float* pos_k    = (const float*)d_in[2];
    const float* pos_q    = (const float*)d_in[3];
    const float* r0       = (const float*)d_in[4];
    const float* W_ak     = (const float*)d_in[5];
    const float* W_vk     = (const float*)d_in[6];
    const float* W_aq     = (const float*)d_in[7];
    const float* W_vq     = (const float*)d_in[8];
    const float* W_aval   = (const float*)d_in[9];
    const float* W_vval   = (const float*)d_in[10];
    const float* W_a2vval = (const float*)d_in[11];
    const float* W_v2aval = (const float*)d_in[12];

    ushort* Kf = (ushort*)d_ws;                        // 8*2048*128
    ushort* Qf = Kf + (size_t)NH * NN * 128;           // 8*2048*128
    ushort* Vt = Qf + (size_t)NH * NN * 128;           // 8*144*2048
    float*  outp = (float*)d_out;

    hipLaunchKernelGGL(proj_kernel, dim3(NN / 8), dim3(1024), 0, stream,
                       ax, vx, pos_k, pos_q, W_ak, W_vk, W_aq, W_vq,
                       W_aval, W_vval, W_a2vval, W_v2aval, Kf, Qf, Vt);
    hipLaunchKernelGGL(attn_kernel, dim3(64 * NH), dim3(512), 0, stream,
                       Kf, Qf, Vt, pos_k, r0, outp);
}

// Round 23
// 94.802 us; speedup vs baseline: 1.1820x; 1.0198x over previous
//
#include <hip/hip_runtime.h>

#define NN 2048
#define NH 8
#define NTASK 2368

typedef __attribute__((ext_vector_type(4))) short s4;
typedef __attribute__((ext_vector_type(8))) short s8;
typedef __attribute__((ext_vector_type(4))) float f4;

static __device__ __forceinline__ ushort f2b(float x) {
    uint u = __builtin_bit_cast(uint, x);
    uint r = (u + 0x7FFFu + ((u >> 16) & 1u)) >> 16;
    return (ushort)r;
}
static __device__ __forceinline__ float b2f(ushort b) {
    return __builtin_bit_cast(float, ((uint)b) << 16);
}
static __device__ __forceinline__ uint pu(ushort a, ushort b) {
    return (uint)a | ((uint)b << 16);
}
// Pure-C bf16x2 pack (RNE). NO inline asm anywhere (rounds 4-10's NaNs were
// an inline-asm producer -> MFMA hazard lottery; builtin-only is safe).
static __device__ __forceinline__ uint bpack(float lo, float hi) {
    return pu(f2b(lo), f2b(hi));
}
static __device__ __forceinline__ s4 pack4(float a, float b, float c, float d) {
    uint2 w; w.x = bpack(a, b); w.y = bpack(c, d);
    return __builtin_bit_cast(s4, w);
}
static __device__ __forceinline__ f4 mfma32(s8 a, s8 b, f4 c) {
    return __builtin_amdgcn_mfma_f32_16x16x32_bf16(a, b, c, 0, 0, 0);
}
static __device__ __forceinline__ f4 mfma16(s4 a, s4 b, f4 c) {
    const s4 z4s = {0, 0, 0, 0};
    s8 a8 = __builtin_shufflevector(a, z4s, 0, 1, 2, 3, 4, 5, 6, 7);
    s8 b8 = __builtin_shufflevector(b, z4s, 0, 1, 2, 3, 4, 5, 6, 7);
    return __builtin_amdgcn_mfma_f32_16x16x32_bf16(a8, b8, c, 0, 0, 0);
}

// Shared task table: weight row base + length for task r (must match proj).
static __device__ __forceinline__ const float* task_wrow(
    int r, int& len,
    const float* W_ak, const float* W_vk, const float* W_aq, const float* W_vq,
    const float* W_aval, const float* W_vval, const float* W_a2vval,
    const float* W_v2aval)
{
    if (r < 256)       { len = 128; return W_ak + r * 128; }
    else if (r < 512)  { len = 128; return W_aq + (r - 256) * 128; }
    else if (r < 896)  { int q = r - 512;  int h = q / 48; int s = q - h * 48; len = 64; return W_vk + (h * 16 + s / 3) * 64; }
    else if (r < 1280) { int q = r - 896;  int h = q / 48; int s = q - h * 48; len = 64; return W_vq + (h * 16 + s / 3) * 64; }
    else if (r < 1408) { len = 128; return W_aval + (r - 1280) * 128; }
    else if (r < 1600) { int q = r - 1408; int h = q / 24; int s = q - h * 24; len = 64; return W_vval + (h * 8 + s / 3) * 64; }
    else if (r < 1984) { int q = r - 1600; int h = q / 48; int s = q - h * 48; len = 64; return W_v2aval + (h * 16 + s / 3) * 64; }
    else if (r < 2048) { len = 128; return W_a2vval + (r - 1984) * 128; }
    else if (r < 2176) { int q = r - 2048; int h = q >> 4; len = 64; return W_v2aval + (h * 16 + (q & 15)) * 64; }
    else               { int q = r - 2176; int h = q / 24; int s = q - h * 24; int i = s / 3; len = 128; return W_a2vval + (h * 8 + i) * 128; }
}

// ---------------------------------------------------------------------------
// Kernel 0: VECTORIZED weight transpose. Wt2[j4][r] is a float4 holding
// w[r][4*j4 .. 4*j4+3]. Thread g = j4*NTASK + r -> 16B write at g*16
// (adjacent g -> contiguous, coalesced). Entries with 4*j4 >= len unread.
// ---------------------------------------------------------------------------
__global__ __launch_bounds__(256) void wtrans_kernel(
    const float* __restrict__ W_ak, const float* __restrict__ W_vk,
    const float* __restrict__ W_aq, const float* __restrict__ W_vq,
    const float* __restrict__ W_aval, const float* __restrict__ W_vval,
    const float* __restrict__ W_a2vval, const float* __restrict__ W_v2aval,
    float* __restrict__ Wt2)
{
    int g = blockIdx.x * 256 + threadIdx.x;
    if (g >= NTASK * 32) return;
    int j4 = g / NTASK, r = g - j4 * NTASK;
    int len;
    const float* wrow = task_wrow(r, len, W_ak, W_vk, W_aq, W_vq,
                                  W_aval, W_vval, W_a2vval, W_v2aval);
    if (4 * j4 < len) {
        float4 v = *(const float4*)(wrow + 4 * j4);
        *(float4*)(Wt2 + (size_t)g * 4) = v;
    }
}

// ---------------------------------------------------------------------------
// Kernel A: merged proj+finish+vtrans (R22 structure, 1024 threads).
// Weight loads now from Wt2: float4 at (j4*NTASK + r)*4 floats — adjacent
// lanes (consecutive r) read adjacent 16B chunks -> fully coalesced.
// ---------------------------------------------------------------------------
__global__ __launch_bounds__(1024) void proj_kernel(
    const float* __restrict__ ax, const float* __restrict__ vx,
    const float* __restrict__ pos_k, const float* __restrict__ pos_q,
    const float* __restrict__ Wt2,
    ushort* __restrict__ Kf, ushort* __restrict__ Qf, ushort* __restrict__ Vt)
{
    __shared__ float axs[8][128];
    __shared__ float vxs[3][8][64];
    __shared__ float xts[8][64];
    __shared__ float pqs[8][3];
    __shared__ __align__(16) ushort kqs[2][8][8][80];   // [dst][node][head][col]
    const int t  = threadIdx.x;
    const int n0 = blockIdx.x * 8;

    if (t < 1024)
        axs[t >> 7][t & 127] = ax[n0 * 128 + t];
    for (int idx = t; idx < 1536; idx += 1024) {
        int nb = idx / 192, r = idx - nb * 192;
        int j = r / 3, v = r - j * 3;
        vxs[v][nb][j] = vx[n0 * 192 + idx];
    }
    if (t < 24) pqs[t / 3][t % 3] = pos_q[n0 * 3 + t];
    __syncthreads();
    if (t < 512) {
        int nb = t >> 6, j = t & 63;
        xts[nb][j] = vxs[0][nb][j] * pqs[nb][0] + vxs[1][nb][j] * pqs[nb][1]
                   + vxs[2][nb][j] * pqs[nb][2];
    }
    __syncthreads();

    #pragma unroll 1
    for (int rr = 0; rr < 3; ++rr) {
        int r = rr * 1024 + t;
        if (r >= NTASK) continue;
        int h, v = 0, col = -1, vrow = -1, dsti = 0, srcT = 0, pv = -1;
        float scale = 1.0f;
        if (r < 256)       { int q = r;        h = q >> 5; srcT = 0; col = q & 31; dsti = 0; }
        else if (r < 512)  { int q = r - 256;  h = q >> 5; srcT = 0; col = q & 31; dsti = 1; scale = 0.1f; }
        else if (r < 896)  { int q = r - 512;  h = q / 48; int s = q - h * 48; v = s % 3; srcT = 1; col = 32 + s; dsti = 0; }
        else if (r < 1280) { int q = r - 896;  h = q / 48; int s = q - h * 48; v = s % 3; srcT = 1; col = 32 + s; dsti = 1; scale = 0.1f; }
        else if (r < 1408) { int q = r - 1280; h = q >> 4; srcT = 0; vrow = q & 15; }
        else if (r < 1600) { int q = r - 1408; h = q / 24; int s = q - h * 24; v = s % 3; srcT = 1; vrow = 16 + s; }
        else if (r < 1984) { int q = r - 1600; h = q / 48; int s = q - h * 48; v = s % 3; srcT = 1; vrow = 48 + s; }
        else if (r < 2048) { int q = r - 1984; h = q >> 3; srcT = 0; vrow = 112 + (q & 7); }
        else if (r < 2176) { int q = r - 2048; h = q >> 4; srcT = 2; vrow = 96 + (q & 15); }
        else               { int q = r - 2176; h = q / 24; int s = q - h * 24; pv = s % 3; srcT = 0; vrow = 120 + s; }

        const float* Wc = Wt2 + (size_t)r * 4;   // float4 for j4 at Wc + j4*NTASK*4
        float acc[8] = {0.f, 0.f, 0.f, 0.f, 0.f, 0.f, 0.f, 0.f};
        if (srcT == 0) {
            for (int j4 = 0; j4 < 32; ++j4) {
                float4 w4 = *(const float4*)(Wc + (size_t)j4 * NTASK * 4);
                #pragma unroll
                for (int nb = 0; nb < 8; ++nb) {
                    float4 x4 = *(const float4*)(&axs[nb][j4 * 4]);
                    acc[nb] += w4.x * x4.x + w4.y * x4.y + w4.z * x4.z + w4.w * x4.w;
                }
            }
        } else {
            const float* sp = (srcT == 1) ? &vxs[v][0][0] : &xts[0][0];
            for (int j4 = 0; j4 < 16; ++j4) {
                float4 w4 = *(const float4*)(Wc + (size_t)j4 * NTASK * 4);
                #pragma unroll
                for (int nb = 0; nb < 8; ++nb) {
                    float4 x4 = *(const float4*)(sp + nb * 64 + j4 * 4);
                    acc[nb] += w4.x * x4.x + w4.y * x4.y + w4.z * x4.z + w4.w * x4.w;
                }
            }
        }
        if (vrow >= 0) {
            float o[8];
            #pragma unroll
            for (int nb = 0; nb < 8; ++nb)
                o[nb] = acc[nb] * (pv >= 0 ? pqs[nb][pv] : 1.0f);
            uint4 pk;
            pk.x = bpack(o[0], o[1]); pk.y = bpack(o[2], o[3]);
            pk.z = bpack(o[4], o[5]); pk.w = bpack(o[6], o[7]);
            *(uint4*)(Vt + ((size_t)(h * 144 + vrow)) * NN + n0) = pk;
        } else {
            #pragma unroll
            for (int nb = 0; nb < 8; ++nb)
                kqs[dsti][nb][h][col] = f2b(scale * acc[nb]);
        }
    }
    __syncthreads();

    // flush Kf/Qf cols 0..79 from staging (coalesced uint4)
    for (int i = t; i < 1280; i += 1024) {
        int dsti = i / 640, rem = i - dsti * 640;
        int row = rem / 10, part = rem - row * 10;
        int h = row >> 3, nb = row & 7;
        uint4 val = *(const uint4*)(&kqs[dsti][nb][h][part * 8]);
        ushort* g = (dsti ? Qf : Kf) + ((size_t)h * NN + n0 + nb) * 128 + part * 8;
        *(uint4*)g = val;
    }

    // merged finish: d2 slot channels (cols 80..127), one thread per (h, nb)
    if (t < 64) {
        int h = t >> 3, nb = t & 7, n = n0 + nb;
        float pqx = pqs[nb][0], pqy = pqs[nb][1], pqz = pqs[nb][2];
        float pkx = pos_k[n * 3], pky = pos_k[n * 3 + 1], pkz = pos_k[n * 3 + 2];

        ushort phx = f2b(pqx), phy = f2b(pqy), phz = f2b(pqz);
        float sq = pqx * pqx + pqy * pqy + pqz * pqz;
        ushort sqh = f2b(sq);
        ushort thx = f2b(pkx), thy = f2b(pky), thz = f2b(pkz);
        ushort qhx = f2b(-2.0f * b2f(thx)), qhy = f2b(-2.0f * b2f(thy)), qhz = f2b(-2.0f * b2f(thz));
        float sk = pkx * pkx + pky * pky + pkz * pkz;
        ushort skh = f2b(sk);

        uint4 z4; z4.x = 0; z4.y = 0; z4.z = 0; z4.w = 0;
        uint4 ka0, ka1;
        ka0.x = pu(phx, f2b(pqx - b2f(phx)));
        ka0.y = pu(phx, phy);
        ka0.z = pu(f2b(pqy - b2f(phy)), phy);
        ka0.w = pu(phz, f2b(pqz - b2f(phz)));
        ka1.x = pu(phz, sqh);
        ka1.y = pu(f2b(sq - b2f(sqh)), 0x3F80);
        ka1.z = pu(0x3F80, 0);
        ka1.w = 0;
        uint4 qa0, qa1;
        qa0.x = pu(qhx, qhx);
        qa0.y = pu(f2b(-2.0f * (pkx - b2f(thx))), qhy);
        qa0.z = pu(qhy, f2b(-2.0f * (pky - b2f(thy))));
        qa0.w = pu(qhz, qhz);
        qa1.x = pu(f2b(-2.0f * (pkz - b2f(thz))), 0x3F80);
        qa1.y = pu(0x3F80, skh);
        qa1.z = pu(f2b(sk - b2f(skh)), 0);
        qa1.w = 0;

        ushort* Ko = Kf + ((size_t)h * NN + n) * 128;
        ushort* Qo = Qf + ((size_t)h * NN + n) * 128;
        *(uint4*)(Ko + 80) = z4;  *(uint4*)(Ko + 88) = z4;
        *(uint4*)(Ko + 96) = ka0; *(uint4*)(Ko + 104) = ka1;
        *(uint4*)(Ko + 112) = z4; *(uint4*)(Ko + 120) = z4;
        *(uint4*)(Qo + 80) = z4;  *(uint4*)(Qo + 88) = z4;
        *(uint4*)(Qo + 96) = qa0; *(uint4*)(Qo + 104) = qa1;
        *(uint4*)(Qo + 112) = z4; *(uint4*)(Qo + 120) = z4;
    } else if (t >= 64 && t < 128) {
        // Vt const rows 40..47 for this block's 8 nodes
        int idx = t - 64, h = idx >> 3, rw = 40 + (idx & 7);
        uint4 cv;
        if (rw == 40) { cv.x = 0x3F803F80u; cv.y = 0x3F803F80u; cv.z = 0x3F803F80u; cv.w = 0x3F803F80u; }
        else          { cv.x = 0; cv.y = 0; cv.z = 0; cv.w = 0; }
        *(uint4*)(Vt + ((size_t)(h * 144 + rw)) * NN + n0) = cv;
    }
}

// ---------------------------------------------------------------------------
// Kernel B (R21/R22-passing text, verbatim): attention. Grid 512; block 512 =
// two independent 4-wave groups on separate key-halves / LDS regions.
// ---------------------------------------------------------------------------
__global__ __launch_bounds__(512, 2) void attn_kernel(
    const ushort* __restrict__ Kf, const ushort* __restrict__ Qf,
    const ushort* __restrict__ Vt, const float* __restrict__ pos_k,
    const float* __restrict__ r0, float* __restrict__ out)
{
    __shared__ __align__(16) char smem[78336];
    const int bid = blockIdx.x;
    const int h = bid & 7;
    const int m0 = (bid >> 3) * 32;
    const int t = threadIdx.x;
    const int wg = t >> 8;           // key-half group (0/1)
    const int tl = t & 255;          // id within group
    const int lane = tl & 63, w = tl >> 6;   // wave in group (0..3)
    const int l15 = lane & 15, lg = lane >> 4;
    const int kh = w >> 1, qh = w & 1;

    const float r0h = r0[h], r0sq = r0h * r0h;
    const ushort* Kg = Kf + (size_t)h * NN * 128;
    const ushort* Vg = Vt + (size_t)h * 144 * NN;

    const ushort* Qp = Qf + ((size_t)h * NN + m0 + qh * 16 + l15) * 128 + lg * 8;
    const s8 qb0 = *(const s8*)(Qp);
    const s8 qb1 = *(const s8*)(Qp + 32);
    const s8 qb2 = *(const s8*)(Qp + 64);
    const s8 qb3 = *(const s8*)(Qp + 96);

    f4 acc[9];
    #pragma unroll
    for (int jb = 0; jb < 9; ++jb) acc[jb] = (f4){0.f, 0.f, 0.f, 0.f};

    char* gbase = smem + wg * 39168;
    const int kbase0 = wg * 1024;    // this group's first key

    uint4 kreg0, kreg1, vreg0, vreg1, vreg2;
    const int kt = tl >> 4, kgr = tl & 15;
    const int vf = tl >> 2, vg = tl & 3;
    const int kc = kgr * 8;
    const int vc = vg * 8;
    const int kS = (((kgr & 8) | ((kgr + kt) & 7))) << 4;
    const int kws0 = kt * 256 + kS;
    const int kws1 = kws0 + 4096;
    const int vS = ((vg + (vf >> 1)) & 3) << 4;
    const int vws0 = vf * 64 + vS;
    const int vws1 = vws0 + 4096;
    const int vws2 = vws0 + 8192;

    const int kro = (kh * 16 + l15) * 256;
    const int e0 = ((lg + l15) & 7) << 4;
    const int e1 = ((lg + l15 + 4) & 7) << 4;
    const int vxo = (((kh * 2 + (lg >> 1) + (l15 >> 1)) & 3) << 4) + ((lg & 1) << 3);

#define LOAD_TILE(k0)                                                               \
    kreg0 = *(const uint4*)(Kg + (size_t)((k0) + kt) * 128 + kc);                   \
    kreg1 = *(const uint4*)(Kg + (size_t)((k0) + 16 + kt) * 128 + kc);              \
    vreg0 = *(const uint4*)(Vg + (size_t)vf * NN + (k0) + vc);                      \
    vreg1 = *(const uint4*)(Vg + (size_t)(vf + 64) * NN + (k0) + vc);               \
    if (tl < 64) vreg2 = *(const uint4*)(Vg + (size_t)(vf + 128) * NN + (k0) + vc);

#define WRITE_TILE(b)                                                               \
  { char* kb_ = gbase + (b) * 17408; char* vb_ = kb_ + 8192;                        \
    *(uint4*)(kb_ + kws0) = kreg0;  *(uint4*)(kb_ + kws1) = kreg1;                  \
    *(uint4*)(vb_ + vws0) = vreg0;  *(uint4*)(vb_ + vws1) = vreg1;                  \
    if (tl < 64) *(uint4*)(vb_ + vws2) = vreg2; }

#define COMPUTE_TILE(b)                                                             \
  { const char* kb_ = gbase + (b) * 17408; const char* vb_ = kb_ + 8192;            \
    const char* kr = kb_ + kro;                                                     \
    s8 ka0 = *(const s8*)(kr + e0);                                                 \
    s8 ka1 = *(const s8*)(kr + e1);                                                 \
    s8 ka2 = *(const s8*)(kr + 128 + e0);                                           \
    s8 ka3 = *(const s8*)(kr + 128 + e1);                                           \
    f4 z = (f4){0.f, 0.f, 0.f, 0.f};                                                \
    f4 dt = mfma32(ka0, qb0, z);                                                    \
    dt = mfma32(ka1, qb1, dt);                                                      \
    dt = mfma32(ka2, qb2, dt);                                                      \
    f4 dd = mfma32(ka3, qb3, z);                                                    \
    float pv[4], gv[4];                                                             \
    _Pragma("unroll")                                                               \
    for (int r = 0; r < 4; ++r) {                                                   \
      float x = r0sq + dd[r];                                                       \
      float rs = __builtin_amdgcn_rsqf(x);                                          \
      float tt = rs * rs;                                                           \
      float y = dt[r];                                                              \
      float e = fmaf(y, fmaf(0.5f, y, 1.0f), 1.0f);                                 \
      pv[r] = r0sq * tt * e;                                                        \
      gv[r] = pv[r] * rs;                                                           \
    }                                                                               \
    s4 pb = pack4(pv[0], pv[1], pv[2], pv[3]);                                      \
    s4 gb = pack4(gv[0], gv[1], gv[2], gv[3]);                                      \
    const char* vr = vb_ + l15 * 64 + vxo;                                          \
    _Pragma("unroll")                                                               \
    for (int jb = 0; jb < 3; ++jb)                                                  \
      acc[jb] = mfma16(*(const s4*)(vr + jb * 1024), pb, acc[jb]);                  \
    _Pragma("unroll")                                                               \
    for (int jb = 3; jb < 9; ++jb)                                                  \
      acc[jb] = mfma16(*(const s4*)(vr + jb * 1024), gb, acc[jb]);                  \
  }

    LOAD_TILE(kbase0)
    WRITE_TILE(0)
    __syncthreads();
    #pragma unroll 2
    for (int tile = 0; tile < 32; ++tile) {
        int b = tile & 1;
        if (tile < 31) { LOAD_TILE(kbase0 + (tile + 1) * 32) }
        COMPUTE_TILE(b)
        __syncthreads();
        if (tile < 31) { WRITE_TILE(b ^ 1) }
        __syncthreads();
    }

    // ---- reduction: intra-group pair (kh), then cross-group (wg), scatter ----
    float* smemf = (float*)smem;
    float my[36];
    #pragma unroll
    for (int jb = 0; jb < 9; ++jb)
        #pragma unroll
        for (int r = 0; r < 4; ++r)
            my[jb * 4 + r] = acc[jb][r];

    if (w >= 2) {
        float* p = smemf + wg * 4736 + ((w - 2) * 64 + lane) * 37;
        #pragma unroll
        for (int i = 0; i < 36; ++i) p[i] = my[i];
    }
    __syncthreads();
    if (w < 2) {
        const float* p = smemf + wg * 4736 + (w * 64 + lane) * 37;
        #pragma unroll
        for (int i = 0; i < 36; ++i) my[i] += p[i];
    }
    __syncthreads();
    if (wg == 1 && w < 2) {
        float* p = smemf + 9472 + (w * 64 + lane) * 37;
        #pragma unroll
        for (int i = 0; i < 36; ++i) p[i] = my[i];
    }
    __syncthreads();
    if (wg == 0 && w < 2) {
        const float* p = smemf + 9472 + (w * 64 + lane) * 37;
        #pragma unroll
        for (int i = 0; i < 36; ++i) my[i] += p[i];
        #pragma unroll
        for (int jb = 0; jb < 9; ++jb)
            #pragma unroll
            for (int r = 0; r < 4; ++r)
                smemf[14208 + ((size_t)w * 144 + jb * 16 + lg * 4 + r) * 17 + l15]
                    = my[jb * 4 + r];
    }
    __syncthreads();

    // ---- epilogue: 512 threads; thread -> (q = t&31, task = t>>5 of 3 outs) ----
    {
        int q = t & 31, task = t >> 5;       // task 0..15
        int m = m0 + q, qh2 = q >> 4, ml = q & 15;
        const float* R = smemf + 14208 + (size_t)qh2 * 144 * 17 + ml;
        float inv = 1.0f / R[40 * 17];
        float pk0 = pos_k[m * 3], pk1 = pos_k[m * 3 + 1], pk2 = pos_k[m * 3 + 2];
        #pragma unroll
        for (int oo = 0; oo < 3; ++oo) {
            int o = task * 3 + oo;
            if (o >= 40) continue;
            if (o < 16) {
                int i = o;
                float val = R[i * 17] + pk0 * R[(48 + 3 * i) * 17] + pk1 * R[(49 + 3 * i) * 17]
                          + pk2 * R[(50 + 3 * i) * 17] - R[(96 + i) * 17];
                out[(size_t)m * 128 + h * 16 + i] = val * inv;
            } else {
                int s = o - 16, ip = s / 3, v3 = s - 3 * ip;
                float pkv = (v3 == 0) ? pk0 : ((v3 == 1) ? pk1 : pk2);
                float val = R[(16 + s) * 17] + pkv * R[(112 + ip) * 17] - R[(120 + s) * 17];
                out[(size_t)NN * 128 + (size_t)m * 192 + h * 24 + s] = val * inv;
            }
        }
    }
#undef LOAD_TILE
#undef WRITE_TILE
#undef COMPUTE_TILE
}

extern "C" void kernel_launch(void* const* d_in, const int* in_sizes, int n_in,
                              void* d_out, int out_size, void* d_ws, size_t ws_size,
                              hipStream_t stream) {
    const float* ax       = (const float*)d_in[0];
    const float* vx       = (const float*)d_in[1];
    const float* pos_k    = (const float*)d_in[2];
    const float* pos_q    = (const float*)d_in[3];
    const float* r0       = (const float*)d_in[4];
    const float* W_ak     = (const float*)d_in[5];
    const float* W_vk     = (const float*)d_in[6];
    const float* W_aq     = (const float*)d_in[7];
    const float* W_vq     = (const float*)d_in[8];
    const float* W_aval   = (const float*)d_in[9];
    const float* W_vval   = (const float*)d_in[10];
    const float* W_a2vval = (const float*)d_in[11];
    const float* W_v2aval = (const float*)d_in[12];

    ushort* Kf = (ushort*)d_ws;                         // 8*2048*128 ushort
    ushort* Qf = Kf + (size_t)NH * NN * 128;            // 8*2048*128 ushort
    ushort* Vt = Qf + (size_t)NH * NN * 128;            // 8*144*2048 ushort
    float*  Wt2 = (float*)(Vt + (size_t)NH * 144 * NN); // 32*NTASK float4
    float*  outp = (float*)d_out;

    hipLaunchKernelGGL(wtrans_kernel, dim3((NTASK * 32 + 255) / 256), dim3(256), 0, stream,
                       W_ak, W_vk, W_aq, W_vq, W_aval, W_vval, W_a2vval, W_v2aval, Wt2);
    hipLaunchKernelGGL(proj_kernel, dim3(NN / 8), dim3(1024), 0, stream,
                       ax, vx, pos_k, pos_q, Wt2, Kf, Qf, Vt);
    hipLaunchKernelGGL(attn_kernel, dim3(64 * NH), dim3(512), 0, stream,
                       Kf, Qf, Vt, pos_k, r0, outp);
}

// Round 24
// 93.176 us; speedup vs baseline: 1.2026x; 1.0175x over previous
//
#include <hip/hip_runtime.h>
#include <hip/hip_bf16.h>

#define NN 2048
#define NH 8
#define NTASK 2368

typedef __attribute__((ext_vector_type(4))) short s4;
typedef __attribute__((ext_vector_type(8))) short s8;
typedef __attribute__((ext_vector_type(4))) float f4;

static __device__ __forceinline__ ushort f2b(float x) {
    uint u = __builtin_bit_cast(uint, x);
    uint r = (u + 0x7FFFu + ((u >> 16) & 1u)) >> 16;
    return (ushort)r;
}
static __device__ __forceinline__ float b2f(ushort b) {
    return __builtin_bit_cast(float, ((uint)b) << 16);
}
static __device__ __forceinline__ uint pu(ushort a, ushort b) {
    return (uint)a | ((uint)b << 16);
}
// bf16x2 pack via the COMPILER-VISIBLE intrinsic (emits v_cvt_pk_bf16_f32
// with hazards handled by the backend; RNE, bit-identical to f2b). Union
// type-pun avoids the __builtin_bit_cast trivially-copyable restriction.
// NO inline asm anywhere (rounds 4-10's NaNs were an inline-asm producer ->
// MFMA hazard lottery; intrinsics are safe).
static __device__ __forceinline__ uint bpack(float lo, float hi) {
    union { __hip_bfloat162 h; uint u; } cv;
    cv.h = __float22bfloat162_rn(make_float2(lo, hi));
    return cv.u;
}
static __device__ __forceinline__ s4 pack4(float a, float b, float c, float d) {
    uint2 w; w.x = bpack(a, b); w.y = bpack(c, d);
    return __builtin_bit_cast(s4, w);
}
static __device__ __forceinline__ f4 mfma32(s8 a, s8 b, f4 c) {
    return __builtin_amdgcn_mfma_f32_16x16x32_bf16(a, b, c, 0, 0, 0);
}
static __device__ __forceinline__ f4 mfma16(s4 a, s4 b, f4 c) {
    const s4 z4s = {0, 0, 0, 0};
    s8 a8 = __builtin_shufflevector(a, z4s, 0, 1, 2, 3, 4, 5, 6, 7);
    s8 b8 = __builtin_shufflevector(b, z4s, 0, 1, 2, 3, 4, 5, 6, 7);
    return __builtin_amdgcn_mfma_f32_16x16x32_bf16(a8, b8, c, 0, 0, 0);
}

// Shared task table: weight row base + length for task r (must match proj).
static __device__ __forceinline__ const float* task_wrow(
    int r, int& len,
    const float* W_ak, const float* W_vk, const float* W_aq, const float* W_vq,
    const float* W_aval, const float* W_vval, const float* W_a2vval,
    const float* W_v2aval)
{
    if (r < 256)       { len = 128; return W_ak + r * 128; }
    else if (r < 512)  { len = 128; return W_aq + (r - 256) * 128; }
    else if (r < 896)  { int q = r - 512;  int h = q / 48; int s = q - h * 48; len = 64; return W_vk + (h * 16 + s / 3) * 64; }
    else if (r < 1280) { int q = r - 896;  int h = q / 48; int s = q - h * 48; len = 64; return W_vq + (h * 16 + s / 3) * 64; }
    else if (r < 1408) { len = 128; return W_aval + (r - 1280) * 128; }
    else if (r < 1600) { int q = r - 1408; int h = q / 24; int s = q - h * 24; len = 64; return W_vval + (h * 8 + s / 3) * 64; }
    else if (r < 1984) { int q = r - 1600; int h = q / 48; int s = q - h * 48; len = 64; return W_v2aval + (h * 16 + s / 3) * 64; }
    else if (r < 2048) { len = 128; return W_a2vval + (r - 1984) * 128; }
    else if (r < 2176) { int q = r - 2048; int h = q >> 4; len = 64; return W_v2aval + (h * 16 + (q & 15)) * 64; }
    else               { int q = r - 2176; int h = q / 24; int s = q - h * 24; int i = s / 3; len = 128; return W_a2vval + (h * 8 + i) * 128; }
}

// ---------------------------------------------------------------------------
// Kernel 0 (R23 verbatim): vectorized weight transpose. Wt2[j4][r] float4.
// ---------------------------------------------------------------------------
__global__ __launch_bounds__(256) void wtrans_kernel(
    const float* __restrict__ W_ak, const float* __restrict__ W_vk,
    const float* __restrict__ W_aq, const float* __restrict__ W_vq,
    const float* __restrict__ W_aval, const float* __restrict__ W_vval,
    const float* __restrict__ W_a2vval, const float* __restrict__ W_v2aval,
    float* __restrict__ Wt2)
{
    int g = blockIdx.x * 256 + threadIdx.x;
    if (g >= NTASK * 32) return;
    int j4 = g / NTASK, r = g - j4 * NTASK;
    int len;
    const float* wrow = task_wrow(r, len, W_ak, W_vk, W_aq, W_vq,
                                  W_aval, W_vval, W_a2vval, W_v2aval);
    if (4 * j4 < len) {
        float4 v = *(const float4*)(wrow + 4 * j4);
        *(float4*)(Wt2 + (size_t)g * 4) = v;
    }
}

// ---------------------------------------------------------------------------
// Kernel A (R23 verbatim): merged proj+finish+vtrans, 1024 threads,
// coalesced Wt2 weight loads.
// ---------------------------------------------------------------------------
__global__ __launch_bounds__(1024) void proj_kernel(
    const float* __restrict__ ax, const float* __restrict__ vx,
    const float* __restrict__ pos_k, const float* __restrict__ pos_q,
    const float* __restrict__ Wt2,
    ushort* __restrict__ Kf, ushort* __restrict__ Qf, ushort* __restrict__ Vt)
{
    __shared__ float axs[8][128];
    __shared__ float vxs[3][8][64];
    __shared__ float xts[8][64];
    __shared__ float pqs[8][3];
    __shared__ __align__(16) ushort kqs[2][8][8][80];   // [dst][node][head][col]
    const int t  = threadIdx.x;
    const int n0 = blockIdx.x * 8;

    if (t < 1024)
        axs[t >> 7][t & 127] = ax[n0 * 128 + t];
    for (int idx = t; idx < 1536; idx += 1024) {
        int nb = idx / 192, r = idx - nb * 192;
        int j = r / 3, v = r - j * 3;
        vxs[v][nb][j] = vx[n0 * 192 + idx];
    }
    if (t < 24) pqs[t / 3][t % 3] = pos_q[n0 * 3 + t];
    __syncthreads();
    if (t < 512) {
        int nb = t >> 6, j = t & 63;
        xts[nb][j] = vxs[0][nb][j] * pqs[nb][0] + vxs[1][nb][j] * pqs[nb][1]
                   + vxs[2][nb][j] * pqs[nb][2];
    }
    __syncthreads();

    #pragma unroll 1
    for (int rr = 0; rr < 3; ++rr) {
        int r = rr * 1024 + t;
        if (r >= NTASK) continue;
        int h, v = 0, col = -1, vrow = -1, dsti = 0, srcT = 0, pv = -1;
        float scale = 1.0f;
        if (r < 256)       { int q = r;        h = q >> 5; srcT = 0; col = q & 31; dsti = 0; }
        else if (r < 512)  { int q = r - 256;  h = q >> 5; srcT = 0; col = q & 31; dsti = 1; scale = 0.1f; }
        else if (r < 896)  { int q = r - 512;  h = q / 48; int s = q - h * 48; v = s % 3; srcT = 1; col = 32 + s; dsti = 0; }
        else if (r < 1280) { int q = r - 896;  h = q / 48; int s = q - h * 48; v = s % 3; srcT = 1; col = 32 + s; dsti = 1; scale = 0.1f; }
        else if (r < 1408) { int q = r - 1280; h = q >> 4; srcT = 0; vrow = q & 15; }
        else if (r < 1600) { int q = r - 1408; h = q / 24; int s = q - h * 24; v = s % 3; srcT = 1; vrow = 16 + s; }
        else if (r < 1984) { int q = r - 1600; h = q / 48; int s = q - h * 48; v = s % 3; srcT = 1; vrow = 48 + s; }
        else if (r < 2048) { int q = r - 1984; h = q >> 3; srcT = 0; vrow = 112 + (q & 7); }
        else if (r < 2176) { int q = r - 2048; h = q >> 4; srcT = 2; vrow = 96 + (q & 15); }
        else               { int q = r - 2176; h = q / 24; int s = q - h * 24; pv = s % 3; srcT = 0; vrow = 120 + s; }

        const float* Wc = Wt2 + (size_t)r * 4;   // float4 for j4 at Wc + j4*NTASK*4
        float acc[8] = {0.f, 0.f, 0.f, 0.f, 0.f, 0.f, 0.f, 0.f};
        if (srcT == 0) {
            for (int j4 = 0; j4 < 32; ++j4) {
                float4 w4 = *(const float4*)(Wc + (size_t)j4 * NTASK * 4);
                #pragma unroll
                for (int nb = 0; nb < 8; ++nb) {
                    float4 x4 = *(const float4*)(&axs[nb][j4 * 4]);
                    acc[nb] += w4.x * x4.x + w4.y * x4.y + w4.z * x4.z + w4.w * x4.w;
                }
            }
        } else {
            const float* sp = (srcT == 1) ? &vxs[v][0][0] : &xts[0][0];
            for (int j4 = 0; j4 < 16; ++j4) {
                float4 w4 = *(const float4*)(Wc + (size_t)j4 * NTASK * 4);
                #pragma unroll
                for (int nb = 0; nb < 8; ++nb) {
                    float4 x4 = *(const float4*)(sp + nb * 64 + j4 * 4);
                    acc[nb] += w4.x * x4.x + w4.y * x4.y + w4.z * x4.z + w4.w * x4.w;
                }
            }
        }
        if (vrow >= 0) {
            float o[8];
            #pragma unroll
            for (int nb = 0; nb < 8; ++nb)
                o[nb] = acc[nb] * (pv >= 0 ? pqs[nb][pv] : 1.0f);
            uint4 pk;
            pk.x = bpack(o[0], o[1]); pk.y = bpack(o[2], o[3]);
            pk.z = bpack(o[4], o[5]); pk.w = bpack(o[6], o[7]);
            *(uint4*)(Vt + ((size_t)(h * 144 + vrow)) * NN + n0) = pk;
        } else {
            #pragma unroll
            for (int nb = 0; nb < 8; ++nb)
                kqs[dsti][nb][h][col] = f2b(scale * acc[nb]);
        }
    }
    __syncthreads();

    // flush Kf/Qf cols 0..79 from staging (coalesced uint4)
    for (int i = t; i < 1280; i += 1024) {
        int dsti = i / 640, rem = i - dsti * 640;
        int row = rem / 10, part = rem - row * 10;
        int h = row >> 3, nb = row & 7;
        uint4 val = *(const uint4*)(&kqs[dsti][nb][h][part * 8]);
        ushort* g = (dsti ? Qf : Kf) + ((size_t)h * NN + n0 + nb) * 128 + part * 8;
        *(uint4*)g = val;
    }

    // merged finish: d2 slot channels (cols 80..127), one thread per (h, nb)
    if (t < 64) {
        int h = t >> 3, nb = t & 7, n = n0 + nb;
        float pqx = pqs[nb][0], pqy = pqs[nb][1], pqz = pqs[nb][2];
        float pkx = pos_k[n * 3], pky = pos_k[n * 3 + 1], pkz = pos_k[n * 3 + 2];

        ushort phx = f2b(pqx), phy = f2b(pqy), phz = f2b(pqz);
        float sq = pqx * pqx + pqy * pqy + pqz * pqz;
        ushort sqh = f2b(sq);
        ushort thx = f2b(pkx), thy = f2b(pky), thz = f2b(pkz);
        ushort qhx = f2b(-2.0f * b2f(thx)), qhy = f2b(-2.0f * b2f(thy)), qhz = f2b(-2.0f * b2f(thz));
        float sk = pkx * pkx + pky * pky + pkz * pkz;
        ushort skh = f2b(sk);

        uint4 z4; z4.x = 0; z4.y = 0; z4.z = 0; z4.w = 0;
        uint4 ka0, ka1;
        ka0.x = pu(phx, f2b(pqx - b2f(phx)));
        ka0.y = pu(phx, phy);
        ka0.z = pu(f2b(pqy - b2f(phy)), phy);
        ka0.w = pu(phz, f2b(pqz - b2f(phz)));
        ka1.x = pu(phz, sqh);
        ka1.y = pu(f2b(sq - b2f(sqh)), 0x3F80);
        ka1.z = pu(0x3F80, 0);
        ka1.w = 0;
        uint4 qa0, qa1;
        qa0.x = pu(qhx, qhx);
        qa0.y = pu(f2b(-2.0f * (pkx - b2f(thx))), qhy);
        qa0.z = pu(qhy, f2b(-2.0f * (pky - b2f(thy))));
        qa0.w = pu(qhz, qhz);
        qa1.x = pu(f2b(-2.0f * (pkz - b2f(thz))), 0x3F80);
        qa1.y = pu(0x3F80, skh);
        qa1.z = pu(f2b(sk - b2f(skh)), 0);
        qa1.w = 0;

        ushort* Ko = Kf + ((size_t)h * NN + n) * 128;
        ushort* Qo = Qf + ((size_t)h * NN + n) * 128;
        *(uint4*)(Ko + 80) = z4;  *(uint4*)(Ko + 88) = z4;
        *(uint4*)(Ko + 96) = ka0; *(uint4*)(Ko + 104) = ka1;
        *(uint4*)(Ko + 112) = z4; *(uint4*)(Ko + 120) = z4;
        *(uint4*)(Qo + 80) = z4;  *(uint4*)(Qo + 88) = z4;
        *(uint4*)(Qo + 96) = qa0; *(uint4*)(Qo + 104) = qa1;
        *(uint4*)(Qo + 112) = z4; *(uint4*)(Qo + 120) = z4;
    } else if (t >= 64 && t < 128) {
        // Vt const rows 40..47 for this block's 8 nodes
        int idx = t - 64, h = idx >> 3, rw = 40 + (idx & 7);
        uint4 cv;
        if (rw == 40) { cv.x = 0x3F803F80u; cv.y = 0x3F803F80u; cv.z = 0x3F803F80u; cv.w = 0x3F803F80u; }
        else          { cv.x = 0; cv.y = 0; cv.z = 0; cv.w = 0; }
        *(uint4*)(Vt + ((size_t)(h * 144 + rw)) * NN + n0) = cv;
    }
}

// ---------------------------------------------------------------------------
// Kernel B (R21/R22/R23-passing text; only the bpack helper changed):
// attention. Grid 512; block 512 = two independent 4-wave groups.
// ---------------------------------------------------------------------------
__global__ __launch_bounds__(512, 2) void attn_kernel(
    const ushort* __restrict__ Kf, const ushort* __restrict__ Qf,
    const ushort* __restrict__ Vt, const float* __restrict__ pos_k,
    const float* __restrict__ r0, float* __restrict__ out)
{
    __shared__ __align__(16) char smem[78336];
    const int bid = blockIdx.x;
    const int h = bid & 7;
    const int m0 = (bid >> 3) * 32;
    const int t = threadIdx.x;
    const int wg = t >> 8;           // key-half group (0/1)
    const int tl = t & 255;          // id within group
    const int lane = tl & 63, w = tl >> 6;   // wave in group (0..3)
    const int l15 = lane & 15, lg = lane >> 4;
    const int kh = w >> 1, qh = w & 1;

    const float r0h = r0[h], r0sq = r0h * r0h;
    const ushort* Kg = Kf + (size_t)h * NN * 128;
    const ushort* Vg = Vt + (size_t)h * 144 * NN;

    const ushort* Qp = Qf + ((size_t)h * NN + m0 + qh * 16 + l15) * 128 + lg * 8;
    const s8 qb0 = *(const s8*)(Qp);
    const s8 qb1 = *(const s8*)(Qp + 32);
    const s8 qb2 = *(const s8*)(Qp + 64);
    const s8 qb3 = *(const s8*)(Qp + 96);

    f4 acc[9];
    #pragma unroll
    for (int jb = 0; jb < 9; ++jb) acc[jb] = (f4){0.f, 0.f, 0.f, 0.f};

    char* gbase = smem + wg * 39168;
    const int kbase0 = wg * 1024;    // this group's first key

    uint4 kreg0, kreg1, vreg0, vreg1, vreg2;
    const int kt = tl >> 4, kgr = tl & 15;
    const int vf = tl >> 2, vg = tl & 3;
    const int kc = kgr * 8;
    const int vc = vg * 8;
    const int kS = (((kgr & 8) | ((kgr + kt) & 7))) << 4;
    const int kws0 = kt * 256 + kS;
    const int kws1 = kws0 + 4096;
    const int vS = ((vg + (vf >> 1)) & 3) << 4;
    const int vws0 = vf * 64 + vS;
    const int vws1 = vws0 + 4096;
    const int vws2 = vws0 + 8192;

    const int kro = (kh * 16 + l15) * 256;
    const int e0 = ((lg + l15) & 7) << 4;
    const int e1 = ((lg + l15 + 4) & 7) << 4;
    const int vxo = (((kh * 2 + (lg >> 1) + (l15 >> 1)) & 3) << 4) + ((lg & 1) << 3);

#define LOAD_TILE(k0)                                                               \
    kreg0 = *(const uint4*)(Kg + (size_t)((k0) + kt) * 128 + kc);                   \
    kreg1 = *(const uint4*)(Kg + (size_t)((k0) + 16 + kt) * 128 + kc);              \
    vreg0 = *(const uint4*)(Vg + (size_t)vf * NN + (k0) + vc);                      \
    vreg1 = *(const uint4*)(Vg + (size_t)(vf + 64) * NN + (k0) + vc);               \
    if (tl < 64) vreg2 = *(const uint4*)(Vg + (size_t)(vf + 128) * NN + (k0) + vc);

#define WRITE_TILE(b)                                                               \
  { char* kb_ = gbase + (b) * 17408; char* vb_ = kb_ + 8192;                        \
    *(uint4*)(kb_ + kws0) = kreg0;  *(uint4*)(kb_ + kws1) = kreg1;                  \
    *(uint4*)(vb_ + vws0) = vreg0;  *(uint4*)(vb_ + vws1) = vreg1;                  \
    if (tl < 64) *(uint4*)(vb_ + vws2) = vreg2; }

#define COMPUTE_TILE(b)                                                             \
  { const char* kb_ = gbase + (b) * 17408; const char* vb_ = kb_ + 8192;            \
    const char* kr = kb_ + kro;                                                     \
    s8 ka0 = *(const s8*)(kr + e0);                                                 \
    s8 ka1 = *(const s8*)(kr + e1);                                                 \
    s8 ka2 = *(const s8*)(kr + 128 + e0);                                           \
    s8 ka3 = *(const s8*)(kr + 128 + e1);                                           \
    f4 z = (f4){0.f, 0.f, 0.f, 0.f};                                                \
    f4 dt = mfma32(ka0, qb0, z);                                                    \
    dt = mfma32(ka1, qb1, dt);                                                      \
    dt = mfma32(ka2, qb2, dt);                                                      \
    f4 dd = mfma32(ka3, qb3, z);                                                    \
    float pv[4], gv[4];                                                             \
    _Pragma("unroll")                                                               \
    for (int r = 0; r < 4; ++r) {                                                   \
      float x = r0sq + dd[r];                                                       \
      float rs = __builtin_amdgcn_rsqf(x);                                          \
      float tt = rs * rs;                                                           \
      float y = dt[r];                                                              \
      float e = fmaf(y, fmaf(0.5f, y, 1.0f), 1.0f);                                 \
      pv[r] = r0sq * tt * e;                                                        \
      gv[r] = pv[r] * rs;                                                           \
    }                                                                               \
    s4 pb = pack4(pv[0], pv[1], pv[2], pv[3]);                                      \
    s4 gb = pack4(gv[0], gv[1], gv[2], gv[3]);                                      \
    const char* vr = vb_ + l15 * 64 + vxo;                                          \
    _Pragma("unroll")                                                               \
    for (int jb = 0; jb < 3; ++jb)                                                  \
      acc[jb] = mfma16(*(const s4*)(vr + jb * 1024), pb, acc[jb]);                  \
    _Pragma("unroll")                                                               \
    for (int jb = 3; jb < 9; ++jb)                                                  \
      acc[jb] = mfma16(*(const s4*)(vr + jb * 1024), gb, acc[jb]);                  \
  }

    LOAD_TILE(kbase0)
    WRITE_TILE(0)
    __syncthreads();
    #pragma unroll 2
    for (int tile = 0; tile < 32; ++tile) {
        int b = tile & 1;
        if (tile < 31) { LOAD_TILE(kbase0 + (tile + 1) * 32) }
        COMPUTE_TILE(b)
        __syncthreads();
        if (tile < 31) { WRITE_TILE(b ^ 1) }
        __syncthreads();
    }

    // ---- reduction: intra-group pair (kh), then cross-group (wg), scatter ----
    float* smemf = (float*)smem;
    float my[36];
    #pragma unroll
    for (int jb = 0; jb < 9; ++jb)
        #pragma unroll
        for (int r = 0; r < 4; ++r)
            my[jb * 4 + r] = acc[jb][r];

    if (w >= 2) {
        float* p = smemf + wg * 4736 + ((w - 2) * 64 + lane) * 37;
        #pragma unroll
        for (int i = 0; i < 36; ++i) p[i] = my[i];
    }
    __syncthreads();
    if (w < 2) {
        const float* p = smemf + wg * 4736 + (w * 64 + lane) * 37;
        #pragma unroll
        for (int i = 0; i < 36; ++i) my[i] += p[i];
    }
    __syncthreads();
    if (wg == 1 && w < 2) {
        float* p = smemf + 9472 + (w * 64 + lane) * 37;
        #pragma unroll
        for (int i = 0; i < 36; ++i) p[i] = my[i];
    }
    __syncthreads();
    if (wg == 0 && w < 2) {
        const float* p = smemf + 9472 + (w * 64 + lane) * 37;
        #pragma unroll
        for (int i = 0; i < 36; ++i) my[i] += p[i];
        #pragma unroll
        for (int jb = 0; jb < 9; ++jb)
            #pragma unroll
            for (int r = 0; r < 4; ++r)
                smemf[14208 + ((size_t)w * 144 + jb * 16 + lg * 4 + r) * 17 + l15]
                    = my[jb * 4 + r];
    }
    __syncthreads();

    // ---- epilogue: 512 threads; thread -> (q = t&31, task = t>>5 of 3 outs) ----
    {
        int q = t & 31, task = t >> 5;       // task 0..15
        int m = m0 + q, qh2 = q >> 4, ml = q & 15;
        const float* R = smemf + 14208 + (size_t)qh2 * 144 * 17 + ml;
        float inv = 1.0f / R[40 * 17];
        float pk0 = pos_k[m * 3], pk1 = pos_k[m * 3 + 1], pk2 = pos_k[m * 3 + 2];
        #pragma unroll
        for (int oo = 0; oo < 3; ++oo) {
            int o = task * 3 + oo;
            if (o >= 40) continue;
            if (o < 16) {
                int i = o;
                float val = R[i * 17] + pk0 * R[(48 + 3 * i) * 17] + pk1 * R[(49 + 3 * i) * 17]
                          + pk2 * R[(50 + 3 * i) * 17] - R[(96 + i) * 17];
                out[(size_t)m * 128 + h * 16 + i] = val * inv;
            } else {
                int s = o - 16, ip = s / 3, v3 = s - 3 * ip;
                float pkv = (v3 == 0) ? pk0 : ((v3 == 1) ? pk1 : pk2);
                float val = R[(16 + s) * 17] + pkv * R[(112 + ip) * 17] - R[(120 + s) * 17];
                out[(size_t)NN * 128 + (size_t)m * 192 + h * 24 + s] = val * inv;
            }
        }
    }
#undef LOAD_TILE
#undef WRITE_TILE
#undef COMPUTE_TILE
}

extern "C" void kernel_launch(void* const* d_in, const int* in_sizes, int n_in,
                              void* d_out, int out_size, void* d_ws, size_t ws_size,
                              hipStream_t stream) {
    const float* ax       = (const float*)d_in[0];
    const float* vx       = (const float*)d_in[1];
    const float* pos_k    = (const float*)d_in[2];
    const float* pos_q    = (const float*)d_in[3];
    const float* r0       = (const float*)d_in[4];
    const float* W_ak     = (const float*)d_in[5];
    const float* W_vk     = (const float*)d_in[6];
    const float* W_aq     = (const float*)d_in[7];
    const float* W_vq     = (const float*)d_in[8];
    const float* W_aval   = (const float*)d_in[9];
    const float* W_vval   = (const float*)d_in[10];
    const float* W_a2vval = (const float*)d_in[11];
    const float* W_v2aval = (const float*)d_in[12];

    ushort* Kf = (ushort*)d_ws;                         // 8*2048*128 ushort
    ushort* Qf = Kf + (size_t)NH * NN * 128;            // 8*2048*128 ushort
    ushort* Vt = Qf + (size_t)NH * NN * 128;            // 8*144*2048 ushort
    float*  Wt2 = (float*)(Vt + (size_t)NH * 144 * NN); // 32*NTASK float4
    float*  outp = (float*)d_out;

    hipLaunchKernelGGL(wtrans_kernel, dim3((NTASK * 32 + 255) / 256), dim3(256), 0, stream,
                       W_ak, W_vk, W_aq, W_vq, W_aval, W_vval, W_a2vval, W_v2aval, Wt2);
    hipLaunchKernelGGL(proj_kernel, dim3(NN / 8), dim3(1024), 0, stream,
                       ax, vx, pos_k, pos_q, Wt2, Kf, Qf, Vt);
    hipLaunchKernelGGL(attn_kernel, dim3(64 * NH), dim3(512), 0, stream,
                       Kf, Qf, Vt, pos_k, r0, outp);
}

// Round 25
// 90.659 us; speedup vs baseline: 1.2360x; 1.0278x over previous
//
#include <hip/hip_runtime.h>
#include <hip/hip_bf16.h>

#define NN 2048
#define NH 8
#define NTASK 2368

typedef __attribute__((ext_vector_type(4))) short s4;
typedef __attribute__((ext_vector_type(8))) short s8;
typedef __attribute__((ext_vector_type(4))) float f4;

static __device__ __forceinline__ ushort f2b(float x) {
    uint u = __builtin_bit_cast(uint, x);
    uint r = (u + 0x7FFFu + ((u >> 16) & 1u)) >> 16;
    return (ushort)r;
}
static __device__ __forceinline__ float b2f(ushort b) {
    return __builtin_bit_cast(float, ((uint)b) << 16);
}
static __device__ __forceinline__ uint pu(ushort a, ushort b) {
    return (uint)a | ((uint)b << 16);
}
// bf16x2 pack via the COMPILER-VISIBLE intrinsic (emits v_cvt_pk_bf16_f32
// with hazards handled by the backend; RNE, bit-identical to f2b).
// NO inline asm anywhere (rounds 4-10's NaNs were an inline-asm producer ->
// MFMA hazard lottery; intrinsics are safe).
static __device__ __forceinline__ uint bpack(float lo, float hi) {
    union { __hip_bfloat162 h; uint u; } cv;
    cv.h = __float22bfloat162_rn(make_float2(lo, hi));
    return cv.u;
}
static __device__ __forceinline__ s4 pack4(float a, float b, float c, float d) {
    uint2 w; w.x = bpack(a, b); w.y = bpack(c, d);
    return __builtin_bit_cast(s4, w);
}
static __device__ __forceinline__ f4 mfma32(s8 a, s8 b, f4 c) {
    return __builtin_amdgcn_mfma_f32_16x16x32_bf16(a, b, c, 0, 0, 0);
}
static __device__ __forceinline__ f4 mfma16(s4 a, s4 b, f4 c) {
    const s4 z4s = {0, 0, 0, 0};
    s8 a8 = __builtin_shufflevector(a, z4s, 0, 1, 2, 3, 4, 5, 6, 7);
    s8 b8 = __builtin_shufflevector(b, z4s, 0, 1, 2, 3, 4, 5, 6, 7);
    return __builtin_amdgcn_mfma_f32_16x16x32_bf16(a8, b8, c, 0, 0, 0);
}

// Shared task table: weight row base + length for task r (must match proj).
static __device__ __forceinline__ const float* task_wrow(
    int r, int& len,
    const float* W_ak, const float* W_vk, const float* W_aq, const float* W_vq,
    const float* W_aval, const float* W_vval, const float* W_a2vval,
    const float* W_v2aval)
{
    if (r < 256)       { len = 128; return W_ak + r * 128; }
    else if (r < 512)  { len = 128; return W_aq + (r - 256) * 128; }
    else if (r < 896)  { int q = r - 512;  int h = q / 48; int s = q - h * 48; len = 64; return W_vk + (h * 16 + s / 3) * 64; }
    else if (r < 1280) { int q = r - 896;  int h = q / 48; int s = q - h * 48; len = 64; return W_vq + (h * 16 + s / 3) * 64; }
    else if (r < 1408) { len = 128; return W_aval + (r - 1280) * 128; }
    else if (r < 1600) { int q = r - 1408; int h = q / 24; int s = q - h * 24; len = 64; return W_vval + (h * 8 + s / 3) * 64; }
    else if (r < 1984) { int q = r - 1600; int h = q / 48; int s = q - h * 48; len = 64; return W_v2aval + (h * 16 + s / 3) * 64; }
    else if (r < 2048) { len = 128; return W_a2vval + (r - 1984) * 128; }
    else if (r < 2176) { int q = r - 2048; int h = q >> 4; len = 64; return W_v2aval + (h * 16 + (q & 15)) * 64; }
    else               { int q = r - 2176; int h = q / 24; int s = q - h * 24; int i = s / 3; len = 128; return W_a2vval + (h * 8 + i) * 128; }
}

// ---------------------------------------------------------------------------
// Kernel 0 (R23/R24 verbatim): vectorized weight transpose. Wt2[j4][r] float4.
// ---------------------------------------------------------------------------
__global__ __launch_bounds__(256) void wtrans_kernel(
    const float* __restrict__ W_ak, const float* __restrict__ W_vk,
    const float* __restrict__ W_aq, const float* __restrict__ W_vq,
    const float* __restrict__ W_aval, const float* __restrict__ W_vval,
    const float* __restrict__ W_a2vval, const float* __restrict__ W_v2aval,
    float* __restrict__ Wt2)
{
    int g = blockIdx.x * 256 + threadIdx.x;
    if (g >= NTASK * 32) return;
    int j4 = g / NTASK, r = g - j4 * NTASK;
    int len;
    const float* wrow = task_wrow(r, len, W_ak, W_vk, W_aq, W_vq,
                                  W_aval, W_vval, W_a2vval, W_v2aval);
    if (4 * j4 < len) {
        float4 v = *(const float4*)(wrow + 4 * j4);
        *(float4*)(Wt2 + (size_t)g * 4) = v;
    }
}

// ---------------------------------------------------------------------------
// Kernel A (R23/R24 verbatim): merged proj+finish+vtrans, 1024 threads,
// coalesced Wt2 weight loads.
// ---------------------------------------------------------------------------
__global__ __launch_bounds__(1024) void proj_kernel(
    const float* __restrict__ ax, const float* __restrict__ vx,
    const float* __restrict__ pos_k, const float* __restrict__ pos_q,
    const float* __restrict__ Wt2,
    ushort* __restrict__ Kf, ushort* __restrict__ Qf, ushort* __restrict__ Vt)
{
    __shared__ float axs[8][128];
    __shared__ float vxs[3][8][64];
    __shared__ float xts[8][64];
    __shared__ float pqs[8][3];
    __shared__ __align__(16) ushort kqs[2][8][8][80];   // [dst][node][head][col]
    const int t  = threadIdx.x;
    const int n0 = blockIdx.x * 8;

    if (t < 1024)
        axs[t >> 7][t & 127] = ax[n0 * 128 + t];
    for (int idx = t; idx < 1536; idx += 1024) {
        int nb = idx / 192, r = idx - nb * 192;
        int j = r / 3, v = r - j * 3;
        vxs[v][nb][j] = vx[n0 * 192 + idx];
    }
    if (t < 24) pqs[t / 3][t % 3] = pos_q[n0 * 3 + t];
    __syncthreads();
    if (t < 512) {
        int nb = t >> 6, j = t & 63;
        xts[nb][j] = vxs[0][nb][j] * pqs[nb][0] + vxs[1][nb][j] * pqs[nb][1]
                   + vxs[2][nb][j] * pqs[nb][2];
    }
    __syncthreads();

    #pragma unroll 1
    for (int rr = 0; rr < 3; ++rr) {
        int r = rr * 1024 + t;
        if (r >= NTASK) continue;
        int h, v = 0, col = -1, vrow = -1, dsti = 0, srcT = 0, pv = -1;
        float scale = 1.0f;
        if (r < 256)       { int q = r;        h = q >> 5; srcT = 0; col = q & 31; dsti = 0; }
        else if (r < 512)  { int q = r - 256;  h = q >> 5; srcT = 0; col = q & 31; dsti = 1; scale = 0.1f; }
        else if (r < 896)  { int q = r - 512;  h = q / 48; int s = q - h * 48; v = s % 3; srcT = 1; col = 32 + s; dsti = 0; }
        else if (r < 1280) { int q = r - 896;  h = q / 48; int s = q - h * 48; v = s % 3; srcT = 1; col = 32 + s; dsti = 1; scale = 0.1f; }
        else if (r < 1408) { int q = r - 1280; h = q >> 4; srcT = 0; vrow = q & 15; }
        else if (r < 1600) { int q = r - 1408; h = q / 24; int s = q - h * 24; v = s % 3; srcT = 1; vrow = 16 + s; }
        else if (r < 1984) { int q = r - 1600; h = q / 48; int s = q - h * 48; v = s % 3; srcT = 1; vrow = 48 + s; }
        else if (r < 2048) { int q = r - 1984; h = q >> 3; srcT = 0; vrow = 112 + (q & 7); }
        else if (r < 2176) { int q = r - 2048; h = q >> 4; srcT = 2; vrow = 96 + (q & 15); }
        else               { int q = r - 2176; h = q / 24; int s = q - h * 24; pv = s % 3; srcT = 0; vrow = 120 + s; }

        const float* Wc = Wt2 + (size_t)r * 4;   // float4 for j4 at Wc + j4*NTASK*4
        float acc[8] = {0.f, 0.f, 0.f, 0.f, 0.f, 0.f, 0.f, 0.f};
        if (srcT == 0) {
            for (int j4 = 0; j4 < 32; ++j4) {
                float4 w4 = *(const float4*)(Wc + (size_t)j4 * NTASK * 4);
                #pragma unroll
                for (int nb = 0; nb < 8; ++nb) {
                    float4 x4 = *(const float4*)(&axs[nb][j4 * 4]);
                    acc[nb] += w4.x * x4.x + w4.y * x4.y + w4.z * x4.z + w4.w * x4.w;
                }
            }
        } else {
            const float* sp = (srcT == 1) ? &vxs[v][0][0] : &xts[0][0];
            for (int j4 = 0; j4 < 16; ++j4) {
                float4 w4 = *(const float4*)(Wc + (size_t)j4 * NTASK * 4);
                #pragma unroll
                for (int nb = 0; nb < 8; ++nb) {
                    float4 x4 = *(const float4*)(sp + nb * 64 + j4 * 4);
                    acc[nb] += w4.x * x4.x + w4.y * x4.y + w4.z * x4.z + w4.w * x4.w;
                }
            }
        }
        if (vrow >= 0) {
            float o[8];
            #pragma unroll
            for (int nb = 0; nb < 8; ++nb)
                o[nb] = acc[nb] * (pv >= 0 ? pqs[nb][pv] : 1.0f);
            uint4 pk;
            pk.x = bpack(o[0], o[1]); pk.y = bpack(o[2], o[3]);
            pk.z = bpack(o[4], o[5]); pk.w = bpack(o[6], o[7]);
            *(uint4*)(Vt + ((size_t)(h * 144 + vrow)) * NN + n0) = pk;
        } else {
            #pragma unroll
            for (int nb = 0; nb < 8; ++nb)
                kqs[dsti][nb][h][col] = f2b(scale * acc[nb]);
        }
    }
    __syncthreads();

    // flush Kf/Qf cols 0..79 from staging (coalesced uint4)
    for (int i = t; i < 1280; i += 1024) {
        int dsti = i / 640, rem = i - dsti * 640;
        int row = rem / 10, part = rem - row * 10;
        int h = row >> 3, nb = row & 7;
        uint4 val = *(const uint4*)(&kqs[dsti][nb][h][part * 8]);
        ushort* g = (dsti ? Qf : Kf) + ((size_t)h * NN + n0 + nb) * 128 + part * 8;
        *(uint4*)g = val;
    }

    // merged finish: d2 slot channels (cols 80..127), one thread per (h, nb)
    if (t < 64) {
        int h = t >> 3, nb = t & 7, n = n0 + nb;
        float pqx = pqs[nb][0], pqy = pqs[nb][1], pqz = pqs[nb][2];
        float pkx = pos_k[n * 3], pky = pos_k[n * 3 + 1], pkz = pos_k[n * 3 + 2];

        ushort phx = f2b(pqx), phy = f2b(pqy), phz = f2b(pqz);
        float sq = pqx * pqx + pqy * pqy + pqz * pqz;
        ushort sqh = f2b(sq);
        ushort thx = f2b(pkx), thy = f2b(pky), thz = f2b(pkz);
        ushort qhx = f2b(-2.0f * b2f(thx)), qhy = f2b(-2.0f * b2f(thy)), qhz = f2b(-2.0f * b2f(thz));
        float sk = pkx * pkx + pky * pky + pkz * pkz;
        ushort skh = f2b(sk);

        uint4 z4; z4.x = 0; z4.y = 0; z4.z = 0; z4.w = 0;
        uint4 ka0, ka1;
        ka0.x = pu(phx, f2b(pqx - b2f(phx)));
        ka0.y = pu(phx, phy);
        ka0.z = pu(f2b(pqy - b2f(phy)), phy);
        ka0.w = pu(phz, f2b(pqz - b2f(phz)));
        ka1.x = pu(phz, sqh);
        ka1.y = pu(f2b(sq - b2f(sqh)), 0x3F80);
        ka1.z = pu(0x3F80, 0);
        ka1.w = 0;
        uint4 qa0, qa1;
        qa0.x = pu(qhx, qhx);
        qa0.y = pu(f2b(-2.0f * (pkx - b2f(thx))), qhy);
        qa0.z = pu(qhy, f2b(-2.0f * (pky - b2f(thy))));
        qa0.w = pu(qhz, qhz);
        qa1.x = pu(f2b(-2.0f * (pkz - b2f(thz))), 0x3F80);
        qa1.y = pu(0x3F80, skh);
        qa1.z = pu(f2b(sk - b2f(skh)), 0);
        qa1.w = 0;

        ushort* Ko = Kf + ((size_t)h * NN + n) * 128;
        ushort* Qo = Qf + ((size_t)h * NN + n) * 128;
        *(uint4*)(Ko + 80) = z4;  *(uint4*)(Ko + 88) = z4;
        *(uint4*)(Ko + 96) = ka0; *(uint4*)(Ko + 104) = ka1;
        *(uint4*)(Ko + 112) = z4; *(uint4*)(Ko + 120) = z4;
        *(uint4*)(Qo + 80) = z4;  *(uint4*)(Qo + 88) = z4;
        *(uint4*)(Qo + 96) = qa0; *(uint4*)(Qo + 104) = qa1;
        *(uint4*)(Qo + 112) = z4; *(uint4*)(Qo + 120) = z4;
    } else if (t >= 64 && t < 128) {
        // Vt const rows 40..47 for this block's 8 nodes
        int idx = t - 64, h = idx >> 3, rw = 40 + (idx & 7);
        uint4 cv;
        if (rw == 40) { cv.x = 0x3F803F80u; cv.y = 0x3F803F80u; cv.z = 0x3F803F80u; cv.w = 0x3F803F80u; }
        else          { cv.x = 0; cv.y = 0; cv.z = 0; cv.w = 0; }
        *(uint4*)(Vt + ((size_t)(h * 144 + rw)) * NN + n0) = cv;
    }
}

// ---------------------------------------------------------------------------
// Kernel B: attention (R24 structure). ONLY change: the redundant mid-tile
// __syncthreads() removed — COMPUTE reads buffer b while WRITE targets b^1
// (disjoint), and the end-of-tile barrier of iteration t-1 already ordered
// all reads of b^1 before its overwrite. One barrier per tile.
// ---------------------------------------------------------------------------
__global__ __launch_bounds__(512, 2) void attn_kernel(
    const ushort* __restrict__ Kf, const ushort* __restrict__ Qf,
    const ushort* __restrict__ Vt, const float* __restrict__ pos_k,
    const float* __restrict__ r0, float* __restrict__ out)
{
    __shared__ __align__(16) char smem[78336];
    const int bid = blockIdx.x;
    const int h = bid & 7;
    const int m0 = (bid >> 3) * 32;
    const int t = threadIdx.x;
    const int wg = t >> 8;           // key-half group (0/1)
    const int tl = t & 255;          // id within group
    const int lane = tl & 63, w = tl >> 6;   // wave in group (0..3)
    const int l15 = lane & 15, lg = lane >> 4;
    const int kh = w >> 1, qh = w & 1;

    const float r0h = r0[h], r0sq = r0h * r0h;
    const ushort* Kg = Kf + (size_t)h * NN * 128;
    const ushort* Vg = Vt + (size_t)h * 144 * NN;

    const ushort* Qp = Qf + ((size_t)h * NN + m0 + qh * 16 + l15) * 128 + lg * 8;
    const s8 qb0 = *(const s8*)(Qp);
    const s8 qb1 = *(const s8*)(Qp + 32);
    const s8 qb2 = *(const s8*)(Qp + 64);
    const s8 qb3 = *(const s8*)(Qp + 96);

    f4 acc[9];
    #pragma unroll
    for (int jb = 0; jb < 9; ++jb) acc[jb] = (f4){0.f, 0.f, 0.f, 0.f};

    char* gbase = smem + wg * 39168;
    const int kbase0 = wg * 1024;    // this group's first key

    uint4 kreg0, kreg1, vreg0, vreg1, vreg2;
    const int kt = tl >> 4, kgr = tl & 15;
    const int vf = tl >> 2, vg = tl & 3;
    const int kc = kgr * 8;
    const int vc = vg * 8;
    const int kS = (((kgr & 8) | ((kgr + kt) & 7))) << 4;
    const int kws0 = kt * 256 + kS;
    const int kws1 = kws0 + 4096;
    const int vS = ((vg + (vf >> 1)) & 3) << 4;
    const int vws0 = vf * 64 + vS;
    const int vws1 = vws0 + 4096;
    const int vws2 = vws0 + 8192;

    const int kro = (kh * 16 + l15) * 256;
    const int e0 = ((lg + l15) & 7) << 4;
    const int e1 = ((lg + l15 + 4) & 7) << 4;
    const int vxo = (((kh * 2 + (lg >> 1) + (l15 >> 1)) & 3) << 4) + ((lg & 1) << 3);

#define LOAD_TILE(k0)                                                               \
    kreg0 = *(const uint4*)(Kg + (size_t)((k0) + kt) * 128 + kc);                   \
    kreg1 = *(const uint4*)(Kg + (size_t)((k0) + 16 + kt) * 128 + kc);              \
    vreg0 = *(const uint4*)(Vg + (size_t)vf * NN + (k0) + vc);                      \
    vreg1 = *(const uint4*)(Vg + (size_t)(vf + 64) * NN + (k0) + vc);               \
    if (tl < 64) vreg2 = *(const uint4*)(Vg + (size_t)(vf + 128) * NN + (k0) + vc);

#define WRITE_TILE(b)                                                               \
  { char* kb_ = gbase + (b) * 17408; char* vb_ = kb_ + 8192;                        \
    *(uint4*)(kb_ + kws0) = kreg0;  *(uint4*)(kb_ + kws1) = kreg1;                  \
    *(uint4*)(vb_ + vws0) = vreg0;  *(uint4*)(vb_ + vws1) = vreg1;                  \
    if (tl < 64) *(uint4*)(vb_ + vws2) = vreg2; }

#define COMPUTE_TILE(b)                                                             \
  { const char* kb_ = gbase + (b) * 17408; const char* vb_ = kb_ + 8192;            \
    const char* kr = kb_ + kro;                                                     \
    s8 ka0 = *(const s8*)(kr + e0);                                                 \
    s8 ka1 = *(const s8*)(kr + e1);                                                 \
    s8 ka2 = *(const s8*)(kr + 128 + e0);                                           \
    s8 ka3 = *(const s8*)(kr + 128 + e1);                                           \
    f4 z = (f4){0.f, 0.f, 0.f, 0.f};                                                \
    f4 dt = mfma32(ka0, qb0, z);                                                    \
    dt = mfma32(ka1, qb1, dt);                                                      \
    dt = mfma32(ka2, qb2, dt);                                                      \
    f4 dd = mfma32(ka3, qb3, z);                                                    \
    float pv[4], gv[4];                                                             \
    _Pragma("unroll")                                                               \
    for (int r = 0; r < 4; ++r) {                                                   \
      float x = r0sq + dd[r];                                                       \
      float rs = __builtin_amdgcn_rsqf(x);                                          \
      float tt = rs * rs;                                                           \
      float y = dt[r];                                                              \
      float e = fmaf(y, fmaf(0.5f, y, 1.0f), 1.0f);                                 \
      pv[r] = r0sq * tt * e;                                                        \
      gv[r] = pv[r] * rs;                                                           \
    }                                                                               \
    s4 pb = pack4(pv[0], pv[1], pv[2], pv[3]);                                      \
    s4 gb = pack4(gv[0], gv[1], gv[2], gv[3]);                                      \
    const char* vr = vb_ + l15 * 64 + vxo;                                          \
    _Pragma("unroll")                                                               \
    for (int jb = 0; jb < 3; ++jb)                                                  \
      acc[jb] = mfma16(*(const s4*)(vr + jb * 1024), pb, acc[jb]);                  \
    _Pragma("unroll")                                                               \
    for (int jb = 3; jb < 9; ++jb)                                                  \
      acc[jb] = mfma16(*(const s4*)(vr + jb * 1024), gb, acc[jb]);                  \
  }

    LOAD_TILE(kbase0)
    WRITE_TILE(0)
    __syncthreads();
    #pragma unroll 2
    for (int tile = 0; tile < 32; ++tile) {
        int b = tile & 1;
        if (tile < 31) { LOAD_TILE(kbase0 + (tile + 1) * 32) }
        COMPUTE_TILE(b)
        if (tile < 31) { WRITE_TILE(b ^ 1) }
        __syncthreads();
    }

    // ---- reduction: intra-group pair (kh), then cross-group (wg), scatter ----
    float* smemf = (float*)smem;
    float my[36];
    #pragma unroll
    for (int jb = 0; jb < 9; ++jb)
        #pragma unroll
        for (int r = 0; r < 4; ++r)
            my[jb * 4 + r] = acc[jb][r];

    if (w >= 2) {
        float* p = smemf + wg * 4736 + ((w - 2) * 64 + lane) * 37;
        #pragma unroll
        for (int i = 0; i < 36; ++i) p[i] = my[i];
    }
    __syncthreads();
    if (w < 2) {
        const float* p = smemf + wg * 4736 + (w * 64 + lane) * 37;
        #pragma unroll
        for (int i = 0; i < 36; ++i) my[i] += p[i];
    }
    __syncthreads();
    if (wg == 1 && w < 2) {
        float* p = smemf + 9472 + (w * 64 + lane) * 37;
        #pragma unroll
        for (int i = 0; i < 36; ++i) p[i] = my[i];
    }
    __syncthreads();
    if (wg == 0 && w < 2) {
        const float* p = smemf + 9472 + (w * 64 + lane) * 37;
        #pragma unroll
        for (int i = 0; i < 36; ++i) my[i] += p[i];
        #pragma unroll
        for (int jb = 0; jb < 9; ++jb)
            #pragma unroll
            for (int r = 0; r < 4; ++r)
                smemf[14208 + ((size_t)w * 144 + jb * 16 + lg * 4 + r) * 17 + l15]
                    = my[jb * 4 + r];
    }
    __syncthreads();

    // ---- epilogue: 512 threads; thread -> (q = t&31, task = t>>5 of 3 outs) ----
    {
        int q = t & 31, task = t >> 5;       // task 0..15
        int m = m0 + q, qh2 = q >> 4, ml = q & 15;
        const float* R = smemf + 14208 + (size_t)qh2 * 144 * 17 + ml;
        float inv = 1.0f / R[40 * 17];
        float pk0 = pos_k[m * 3], pk1 = pos_k[m * 3 + 1], pk2 = pos_k[m * 3 + 2];
        #pragma unroll
        for (int oo = 0; oo < 3; ++oo) {
            int o = task * 3 + oo;
            if (o >= 40) continue;
            if (o < 16) {
                int i = o;
                float val = R[i * 17] + pk0 * R[(48 + 3 * i) * 17] + pk1 * R[(49 + 3 * i) * 17]
                          + pk2 * R[(50 + 3 * i) * 17] - R[(96 + i) * 17];
                out[(size_t)m * 128 + h * 16 + i] = val * inv;
            } else {
                int s = o - 16, ip = s / 3, v3 = s - 3 * ip;
                float pkv = (v3 == 0) ? pk0 : ((v3 == 1) ? pk1 : pk2);
                float val = R[(16 + s) * 17] + pkv * R[(112 + ip) * 17] - R[(120 + s) * 17];
                out[(size_t)NN * 128 + (size_t)m * 192 + h * 24 + s] = val * inv;
            }
        }
    }
#undef LOAD_TILE
#undef WRITE_TILE
#undef COMPUTE_TILE
}

extern "C" void kernel_launch(void* const* d_in, const int* in_sizes, int n_in,
                              void* d_out, int out_size, void* d_ws, size_t ws_size,
                              hipStream_t stream) {
    const float* ax       = (const float*)d_in[0];
    const float* vx       = (const float*)d_in[1];
    const float* pos_k    = (const float*)d_in[2];
    const float* pos_q    = (const float*)d_in[3];
    const float* r0       = (const float*)d_in[4];
    const float* W_ak     = (const float*)d_in[5];
    const float* W_vk     = (const float*)d_in[6];
    const float* W_aq     = (const float*)d_in[7];
    const float* W_vq     = (const float*)d_in[8];
    const float* W_aval   = (const float*)d_in[9];
    const float* W_vval   = (const float*)d_in[10];
    const float* W_a2vval = (const float*)d_in[11];
    const float* W_v2aval = (const float*)d_in[12];

    ushort* Kf = (ushort*)d_ws;                         // 8*2048*128 ushort
    ushort* Qf = Kf + (size_t)NH * NN * 128;            // 8*2048*128 ushort
    ushort* Vt = Qf + (size_t)NH * NN * 128;            // 8*144*2048 ushort
    float*  Wt2 = (float*)(Vt + (size_t)NH * 144 * NN); // 32*NTASK float4
    float*  outp = (float*)d_out;

    hipLaunchKernelGGL(wtrans_kernel, dim3((NTASK * 32 + 255) / 256), dim3(256), 0, stream,
                       W_ak, W_vk, W_aq, W_vq, W_aval, W_vval, W_a2vval, W_v2aval, Wt2);
    hipLaunchKernelGGL(proj_kernel, dim3(NN / 8), dim3(1024), 0, stream,
                       ax, vx, pos_k, pos_q, Wt2, Kf, Qf, Vt);
    hipLaunchKernelGGL(attn_kernel, dim3(64 * NH), dim3(512), 0, stream,
                       Kf, Qf, Vt, pos_k, r0, outp);
}

// Round 26
// 89.443 us; speedup vs baseline: 1.2528x; 1.0136x over previous
//
#include <hip/hip_runtime.h>
#include <hip/hip_bf16.h>

#define NN 2048
#define NH 8
#define NTASK 2368

typedef __attribute__((ext_vector_type(4))) short s4;
typedef __attribute__((ext_vector_type(8))) short s8;
typedef __attribute__((ext_vector_type(4))) float f4;

static __device__ __forceinline__ ushort f2b(float x) {
    uint u = __builtin_bit_cast(uint, x);
    uint r = (u + 0x7FFFu + ((u >> 16) & 1u)) >> 16;
    return (ushort)r;
}
static __device__ __forceinline__ float b2f(ushort b) {
    return __builtin_bit_cast(float, ((uint)b) << 16);
}
static __device__ __forceinline__ uint pu(ushort a, ushort b) {
    return (uint)a | ((uint)b << 16);
}
// bf16x2 pack via the COMPILER-VISIBLE intrinsic (emits v_cvt_pk_bf16_f32
// with hazards handled by the backend; RNE, bit-identical to f2b).
// NO inline asm anywhere (rounds 4-10's NaNs were an inline-asm producer ->
// MFMA hazard lottery; intrinsics are safe).
static __device__ __forceinline__ uint bpack(float lo, float hi) {
    union { __hip_bfloat162 h; uint u; } cv;
    cv.h = __float22bfloat162_rn(make_float2(lo, hi));
    return cv.u;
}
static __device__ __forceinline__ s4 pack4(float a, float b, float c, float d) {
    uint2 w; w.x = bpack(a, b); w.y = bpack(c, d);
    return __builtin_bit_cast(s4, w);
}
static __device__ __forceinline__ f4 mfma32(s8 a, s8 b, f4 c) {
    return __builtin_amdgcn_mfma_f32_16x16x32_bf16(a, b, c, 0, 0, 0);
}
static __device__ __forceinline__ f4 mfma16(s4 a, s4 b, f4 c) {
    const s4 z4s = {0, 0, 0, 0};
    s8 a8 = __builtin_shufflevector(a, z4s, 0, 1, 2, 3, 4, 5, 6, 7);
    s8 b8 = __builtin_shufflevector(b, z4s, 0, 1, 2, 3, 4, 5, 6, 7);
    return __builtin_amdgcn_mfma_f32_16x16x32_bf16(a8, b8, c, 0, 0, 0);
}

// Shared task table: weight row base + length for task r (must match proj).
static __device__ __forceinline__ const float* task_wrow(
    int r, int& len,
    const float* W_ak, const float* W_vk, const float* W_aq, const float* W_vq,
    const float* W_aval, const float* W_vval, const float* W_a2vval,
    const float* W_v2aval)
{
    if (r < 256)       { len = 128; return W_ak + r * 128; }
    else if (r < 512)  { len = 128; return W_aq + (r - 256) * 128; }
    else if (r < 896)  { int q = r - 512;  int h = q / 48; int s = q - h * 48; len = 64; return W_vk + (h * 16 + s / 3) * 64; }
    else if (r < 1280) { int q = r - 896;  int h = q / 48; int s = q - h * 48; len = 64; return W_vq + (h * 16 + s / 3) * 64; }
    else if (r < 1408) { len = 128; return W_aval + (r - 1280) * 128; }
    else if (r < 1600) { int q = r - 1408; int h = q / 24; int s = q - h * 24; len = 64; return W_vval + (h * 8 + s / 3) * 64; }
    else if (r < 1984) { int q = r - 1600; int h = q / 48; int s = q - h * 48; len = 64; return W_v2aval + (h * 16 + s / 3) * 64; }
    else if (r < 2048) { len = 128; return W_a2vval + (r - 1984) * 128; }
    else if (r < 2176) { int q = r - 2048; int h = q >> 4; len = 64; return W_v2aval + (h * 16 + (q & 15)) * 64; }
    else               { int q = r - 2176; int h = q / 24; int s = q - h * 24; int i = s / 3; len = 128; return W_a2vval + (h * 8 + i) * 128; }
}

// ---------------------------------------------------------------------------
// Kernel 0 (verbatim): vectorized weight transpose. Wt2[j4][r] float4.
// ---------------------------------------------------------------------------
__global__ __launch_bounds__(256) void wtrans_kernel(
    const float* __restrict__ W_ak, const float* __restrict__ W_vk,
    const float* __restrict__ W_aq, const float* __restrict__ W_vq,
    const float* __restrict__ W_aval, const float* __restrict__ W_vval,
    const float* __restrict__ W_a2vval, const float* __restrict__ W_v2aval,
    float* __restrict__ Wt2)
{
    int g = blockIdx.x * 256 + threadIdx.x;
    if (g >= NTASK * 32) return;
    int j4 = g / NTASK, r = g - j4 * NTASK;
    int len;
    const float* wrow = task_wrow(r, len, W_ak, W_vk, W_aq, W_vq,
                                  W_aval, W_vval, W_a2vval, W_v2aval);
    if (4 * j4 < len) {
        float4 v = *(const float4*)(wrow + 4 * j4);
        *(float4*)(Wt2 + (size_t)g * 4) = v;
    }
}

// ---------------------------------------------------------------------------
// Kernel A: merged proj+finish+vtrans (R25 structure). ONLY change: vxs
// planes padded to 520-dword stride (was 512 == 0 mod 32 -> all three
// v-planes on the same banks -> 3-way conflict on per-lane v reads, which
// hit 1344/2368 tasks). 520 % 32 = 8 -> disjoint bank quads, conflict-free.
// ---------------------------------------------------------------------------
__global__ __launch_bounds__(1024) void proj_kernel(
    const float* __restrict__ ax, const float* __restrict__ vx,
    const float* __restrict__ pos_k, const float* __restrict__ pos_q,
    const float* __restrict__ Wt2,
    ushort* __restrict__ Kf, ushort* __restrict__ Qf, ushort* __restrict__ Vt)
{
    __shared__ float axs[8][128];
    __shared__ float vxs[3][520];   // plane stride 520 dwords (bank-offset 8)
    __shared__ float xts[8][64];
    __shared__ float pqs[8][3];
    __shared__ __align__(16) ushort kqs[2][8][8][80];   // [dst][node][head][col]
    const int t  = threadIdx.x;
    const int n0 = blockIdx.x * 8;

    if (t < 1024)
        axs[t >> 7][t & 127] = ax[n0 * 128 + t];
    for (int idx = t; idx < 1536; idx += 1024) {
        int nb = idx / 192, r = idx - nb * 192;
        int j = r / 3, v = r - j * 3;
        vxs[v][nb * 64 + j] = vx[n0 * 192 + idx];
    }
    if (t < 24) pqs[t / 3][t % 3] = pos_q[n0 * 3 + t];
    __syncthreads();
    if (t < 512) {
        int nb = t >> 6, j = t & 63;
        xts[nb][j] = vxs[0][nb * 64 + j] * pqs[nb][0] + vxs[1][nb * 64 + j] * pqs[nb][1]
                   + vxs[2][nb * 64 + j] * pqs[nb][2];
    }
    __syncthreads();

    #pragma unroll 1
    for (int rr = 0; rr < 3; ++rr) {
        int r = rr * 1024 + t;
        if (r >= NTASK) continue;
        int h, v = 0, col = -1, vrow = -1, dsti = 0, srcT = 0, pv = -1;
        float scale = 1.0f;
        if (r < 256)       { int q = r;        h = q >> 5; srcT = 0; col = q & 31; dsti = 0; }
        else if (r < 512)  { int q = r - 256;  h = q >> 5; srcT = 0; col = q & 31; dsti = 1; scale = 0.1f; }
        else if (r < 896)  { int q = r - 512;  h = q / 48; int s = q - h * 48; v = s % 3; srcT = 1; col = 32 + s; dsti = 0; }
        else if (r < 1280) { int q = r - 896;  h = q / 48; int s = q - h * 48; v = s % 3; srcT = 1; col = 32 + s; dsti = 1; scale = 0.1f; }
        else if (r < 1408) { int q = r - 1280; h = q >> 4; srcT = 0; vrow = q & 15; }
        else if (r < 1600) { int q = r - 1408; h = q / 24; int s = q - h * 24; v = s % 3; srcT = 1; vrow = 16 + s; }
        else if (r < 1984) { int q = r - 1600; h = q / 48; int s = q - h * 48; v = s % 3; srcT = 1; vrow = 48 + s; }
        else if (r < 2048) { int q = r - 1984; h = q >> 3; srcT = 0; vrow = 112 + (q & 7); }
        else if (r < 2176) { int q = r - 2048; h = q >> 4; srcT = 2; vrow = 96 + (q & 15); }
        else               { int q = r - 2176; h = q / 24; int s = q - h * 24; pv = s % 3; srcT = 0; vrow = 120 + s; }

        const float* Wc = Wt2 + (size_t)r * 4;   // float4 for j4 at Wc + j4*NTASK*4
        float acc[8] = {0.f, 0.f, 0.f, 0.f, 0.f, 0.f, 0.f, 0.f};
        if (srcT == 0) {
            for (int j4 = 0; j4 < 32; ++j4) {
                float4 w4 = *(const float4*)(Wc + (size_t)j4 * NTASK * 4);
                #pragma unroll
                for (int nb = 0; nb < 8; ++nb) {
                    float4 x4 = *(const float4*)(&axs[nb][j4 * 4]);
                    acc[nb] += w4.x * x4.x + w4.y * x4.y + w4.z * x4.z + w4.w * x4.w;
                }
            }
        } else {
            const float* sp = (srcT == 1) ? &vxs[v][0] : &xts[0][0];
            for (int j4 = 0; j4 < 16; ++j4) {
                float4 w4 = *(const float4*)(Wc + (size_t)j4 * NTASK * 4);
                #pragma unroll
                for (int nb = 0; nb < 8; ++nb) {
                    float4 x4 = *(const float4*)(sp + nb * 64 + j4 * 4);
                    acc[nb] += w4.x * x4.x + w4.y * x4.y + w4.z * x4.z + w4.w * x4.w;
                }
            }
        }
        if (vrow >= 0) {
            float o[8];
            #pragma unroll
            for (int nb = 0; nb < 8; ++nb)
                o[nb] = acc[nb] * (pv >= 0 ? pqs[nb][pv] : 1.0f);
            uint4 pk;
            pk.x = bpack(o[0], o[1]); pk.y = bpack(o[2], o[3]);
            pk.z = bpack(o[4], o[5]); pk.w = bpack(o[6], o[7]);
            *(uint4*)(Vt + ((size_t)(h * 144 + vrow)) * NN + n0) = pk;
        } else {
            #pragma unroll
            for (int nb = 0; nb < 8; ++nb)
                kqs[dsti][nb][h][col] = f2b(scale * acc[nb]);
        }
    }
    __syncthreads();

    // flush Kf/Qf cols 0..79 from staging (coalesced uint4)
    for (int i = t; i < 1280; i += 1024) {
        int dsti = i / 640, rem = i - dsti * 640;
        int row = rem / 10, part = rem - row * 10;
        int h = row >> 3, nb = row & 7;
        uint4 val = *(const uint4*)(&kqs[dsti][nb][h][part * 8]);
        ushort* g = (dsti ? Qf : Kf) + ((size_t)h * NN + n0 + nb) * 128 + part * 8;
        *(uint4*)g = val;
    }

    // merged finish: d2 slot channels (cols 80..127), one thread per (h, nb)
    if (t < 64) {
        int h = t >> 3, nb = t & 7, n = n0 + nb;
        float pqx = pqs[nb][0], pqy = pqs[nb][1], pqz = pqs[nb][2];
        float pkx = pos_k[n * 3], pky = pos_k[n * 3 + 1], pkz = pos_k[n * 3 + 2];

        ushort phx = f2b(pqx), phy = f2b(pqy), phz = f2b(pqz);
        float sq = pqx * pqx + pqy * pqy + pqz * pqz;
        ushort sqh = f2b(sq);
        ushort thx = f2b(pkx), thy = f2b(pky), thz = f2b(pkz);
        ushort qhx = f2b(-2.0f * b2f(thx)), qhy = f2b(-2.0f * b2f(thy)), qhz = f2b(-2.0f * b2f(thz));
        float sk = pkx * pkx + pky * pky + pkz * pkz;
        ushort skh = f2b(sk);

        uint4 z4; z4.x = 0; z4.y = 0; z4.z = 0; z4.w = 0;
        uint4 ka0, ka1;
        ka0.x = pu(phx, f2b(pqx - b2f(phx)));
        ka0.y = pu(phx, phy);
        ka0.z = pu(f2b(pqy - b2f(phy)), phy);
        ka0.w = pu(phz, f2b(pqz - b2f(phz)));
        ka1.x = pu(phz, sqh);
        ka1.y = pu(f2b(sq - b2f(sqh)), 0x3F80);
        ka1.z = pu(0x3F80, 0);
        ka1.w = 0;
        uint4 qa0, qa1;
        qa0.x = pu(qhx, qhx);
        qa0.y = pu(f2b(-2.0f * (pkx - b2f(thx))), qhy);
        qa0.z = pu(qhy, f2b(-2.0f * (pky - b2f(thy))));
        qa0.w = pu(qhz, qhz);
        qa1.x = pu(f2b(-2.0f * (pkz - b2f(thz))), 0x3F80);
        qa1.y = pu(0x3F80, skh);
        qa1.z = pu(f2b(sk - b2f(skh)), 0);
        qa1.w = 0;

        ushort* Ko = Kf + ((size_t)h * NN + n) * 128;
        ushort* Qo = Qf + ((size_t)h * NN + n) * 128;
        *(uint4*)(Ko + 80) = z4;  *(uint4*)(Ko + 88) = z4;
        *(uint4*)(Ko + 96) = ka0; *(uint4*)(Ko + 104) = ka1;
        *(uint4*)(Ko + 112) = z4; *(uint4*)(Ko + 120) = z4;
        *(uint4*)(Qo + 80) = z4;  *(uint4*)(Qo + 88) = z4;
        *(uint4*)(Qo + 96) = qa0; *(uint4*)(Qo + 104) = qa1;
        *(uint4*)(Qo + 112) = z4; *(uint4*)(Qo + 120) = z4;
    } else if (t >= 64 && t < 128) {
        // Vt const rows 40..47 for this block's 8 nodes
        int idx = t - 64, h = idx >> 3, rw = 40 + (idx & 7);
        uint4 cv;
        if (rw == 40) { cv.x = 0x3F803F80u; cv.y = 0x3F803F80u; cv.z = 0x3F803F80u; cv.w = 0x3F803F80u; }
        else          { cv.x = 0; cv.y = 0; cv.z = 0; cv.w = 0; }
        *(uint4*)(Vt + ((size_t)(h * 144 + rw)) * NN + n0) = cv;
    }
}

// ---------------------------------------------------------------------------
// Kernel B (R25-passing text, verbatim): attention. Grid 512; block 512 =
// two independent 4-wave groups; one barrier per tile (dbuf-safe).
// ---------------------------------------------------------------------------
__global__ __launch_bounds__(512, 2) void attn_kernel(
    const ushort* __restrict__ Kf, const ushort* __restrict__ Qf,
    const ushort* __restrict__ Vt, const float* __restrict__ pos_k,
    const float* __restrict__ r0, float* __restrict__ out)
{
    __shared__ __align__(16) char smem[78336];
    const int bid = blockIdx.x;
    const int h = bid & 7;
    const int m0 = (bid >> 3) * 32;
    const int t = threadIdx.x;
    const int wg = t >> 8;           // key-half group (0/1)
    const int tl = t & 255;          // id within group
    const int lane = tl & 63, w = tl >> 6;   // wave in group (0..3)
    const int l15 = lane & 15, lg = lane >> 4;
    const int kh = w >> 1, qh = w & 1;

    const float r0h = r0[h], r0sq = r0h * r0h;
    const ushort* Kg = Kf + (size_t)h * NN * 128;
    const ushort* Vg = Vt + (size_t)h * 144 * NN;

    const ushort* Qp = Qf + ((size_t)h * NN + m0 + qh * 16 + l15) * 128 + lg * 8;
    const s8 qb0 = *(const s8*)(Qp);
    const s8 qb1 = *(const s8*)(Qp + 32);
    const s8 qb2 = *(const s8*)(Qp + 64);
    const s8 qb3 = *(const s8*)(Qp + 96);

    f4 acc[9];
    #pragma unroll
    for (int jb = 0; jb < 9; ++jb) acc[jb] = (f4){0.f, 0.f, 0.f, 0.f};

    char* gbase = smem + wg * 39168;
    const int kbase0 = wg * 1024;    // this group's first key

    uint4 kreg0, kreg1, vreg0, vreg1, vreg2;
    const int kt = tl >> 4, kgr = tl & 15;
    const int vf = tl >> 2, vg = tl & 3;
    const int kc = kgr * 8;
    const int vc = vg * 8;
    const int kS = (((kgr & 8) | ((kgr + kt) & 7))) << 4;
    const int kws0 = kt * 256 + kS;
    const int kws1 = kws0 + 4096;
    const int vS = ((vg + (vf >> 1)) & 3) << 4;
    const int vws0 = vf * 64 + vS;
    const int vws1 = vws0 + 4096;
    const int vws2 = vws0 + 8192;

    const int kro = (kh * 16 + l15) * 256;
    const int e0 = ((lg + l15) & 7) << 4;
    const int e1 = ((lg + l15 + 4) & 7) << 4;
    const int vxo = (((kh * 2 + (lg >> 1) + (l15 >> 1)) & 3) << 4) + ((lg & 1) << 3);

#define LOAD_TILE(k0)                                                               \
    kreg0 = *(const uint4*)(Kg + (size_t)((k0) + kt) * 128 + kc);                   \
    kreg1 = *(const uint4*)(Kg + (size_t)((k0) + 16 + kt) * 128 + kc);              \
    vreg0 = *(const uint4*)(Vg + (size_t)vf * NN + (k0) + vc);                      \
    vreg1 = *(const uint4*)(Vg + (size_t)(vf + 64) * NN + (k0) + vc);               \
    if (tl < 64) vreg2 = *(const uint4*)(Vg + (size_t)(vf + 128) * NN + (k0) + vc);

#define WRITE_TILE(b)                                                               \
  { char* kb_ = gbase + (b) * 17408; char* vb_ = kb_ + 8192;                        \
    *(uint4*)(kb_ + kws0) = kreg0;  *(uint4*)(kb_ + kws1) = kreg1;                  \
    *(uint4*)(vb_ + vws0) = vreg0;  *(uint4*)(vb_ + vws1) = vreg1;                  \
    if (tl < 64) *(uint4*)(vb_ + vws2) = vreg2; }

#define COMPUTE_TILE(b)                                                             \
  { const char* kb_ = gbase + (b) * 17408; const char* vb_ = kb_ + 8192;            \
    const char* kr = kb_ + kro;                                                     \
    s8 ka0 = *(const s8*)(kr + e0);                                                 \
    s8 ka1 = *(const s8*)(kr + e1);                                                 \
    s8 ka2 = *(const s8*)(kr + 128 + e0);                                           \
    s8 ka3 = *(const s8*)(kr + 128 + e1);                                           \
    f4 z = (f4){0.f, 0.f, 0.f, 0.f};                                                \
    f4 dt = mfma32(ka0, qb0, z);                                                    \
    dt = mfma32(ka1, qb1, dt);                                                      \
    dt = mfma32(ka2, qb2, dt);                                                      \
    f4 dd = mfma32(ka3, qb3, z);                                                    \
    float pv[4], gv[4];                                                             \
    _Pragma("unroll")                                                               \
    for (int r = 0; r < 4; ++r) {                                                   \
      float x = r0sq + dd[r];                                                       \
      float rs = __builtin_amdgcn_rsqf(x);                                          \
      float tt = rs * rs;                                                           \
      float y = dt[r];                                                              \
      float e = fmaf(y, fmaf(0.5f, y, 1.0f), 1.0f);                                 \
      pv[r] = r0sq * tt * e;                                                        \
      gv[r] = pv[r] * rs;                                                           \
    }                                                                               \
    s4 pb = pack4(pv[0], pv[1], pv[2], pv[3]);                                      \
    s4 gb = pack4(gv[0], gv[1], gv[2], gv[3]);                                      \
    const char* vr = vb_ + l15 * 64 + vxo;                                          \
    _Pragma("unroll")                                                               \
    for (int jb = 0; jb < 3; ++jb)                                                  \
      acc[jb] = mfma16(*(const s4*)(vr + jb * 1024), pb, acc[jb]);                  \
    _Pragma("unroll")                                                               \
    for (int jb = 3; jb < 9; ++jb)                                                  \
      acc[jb] = mfma16(*(const s4*)(vr + jb * 1024), gb, acc[jb]);                  \
  }

    LOAD_TILE(kbase0)
    WRITE_TILE(0)
    __syncthreads();
    #pragma unroll 2
    for (int tile = 0; tile < 32; ++tile) {
        int b = tile & 1;
        if (tile < 31) { LOAD_TILE(kbase0 + (tile + 1) * 32) }
        COMPUTE_TILE(b)
        if (tile < 31) { WRITE_TILE(b ^ 1) }
        __syncthreads();
    }

    // ---- reduction: intra-group pair (kh), then cross-group (wg), scatter ----
    float* smemf = (float*)smem;
    float my[36];
    #pragma unroll
    for (int jb = 0; jb < 9; ++jb)
        #pragma unroll
        for (int r = 0; r < 4; ++r)
            my[jb * 4 + r] = acc[jb][r];

    if (w >= 2) {
        float* p = smemf + wg * 4736 + ((w - 2) * 64 + lane) * 37;
        #pragma unroll
        for (int i = 0; i < 36; ++i) p[i] = my[i];
    }
    __syncthreads();
    if (w < 2) {
        const float* p = smemf + wg * 4736 + (w * 64 + lane) * 37;
        #pragma unroll
        for (int i = 0; i < 36; ++i) my[i] += p[i];
    }
    __syncthreads();
    if (wg == 1 && w < 2) {
        float* p = smemf + 9472 + (w * 64 + lane) * 37;
        #pragma unroll
        for (int i = 0; i < 36; ++i) p[i] = my[i];
    }
    __syncthreads();
    if (wg == 0 && w < 2) {
        const float* p = smemf + 9472 + (w * 64 + lane) * 37;
        #pragma unroll
        for (int i = 0; i < 36; ++i) my[i] += p[i];
        #pragma unroll
        for (int jb = 0; jb < 9; ++jb)
            #pragma unroll
            for (int r = 0; r < 4; ++r)
                smemf[14208 + ((size_t)w * 144 + jb * 16 + lg * 4 + r) * 17 + l15]
                    = my[jb * 4 + r];
    }
    __syncthreads();

    // ---- epilogue: 512 threads; thread -> (q = t&31, task = t>>5 of 3 outs) ----
    {
        int q = t & 31, task = t >> 5;       // task 0..15
        int m = m0 + q, qh2 = q >> 4, ml = q & 15;
        const float* R = smemf + 14208 + (size_t)qh2 * 144 * 17 + ml;
        float inv = 1.0f / R[40 * 17];
        float pk0 = pos_k[m * 3], pk1 = pos_k[m * 3 + 1], pk2 = pos_k[m * 3 + 2];
        #pragma unroll
        for (int oo = 0; oo < 3; ++oo) {
            int o = task * 3 + oo;
            if (o >= 40) continue;
            if (o < 16) {
                int i = o;
                float val = R[i * 17] + pk0 * R[(48 + 3 * i) * 17] + pk1 * R[(49 + 3 * i) * 17]
                          + pk2 * R[(50 + 3 * i) * 17] - R[(96 + i) * 17];
                out[(size_t)m * 128 + h * 16 + i] = val * inv;
            } else {
                int s = o - 16, ip = s / 3, v3 = s - 3 * ip;
                float pkv = (v3 == 0) ? pk0 : ((v3 == 1) ? pk1 : pk2);
                float val = R[(16 + s) * 17] + pkv * R[(112 + ip) * 17] - R[(120 + s) * 17];
                out[(size_t)NN * 128 + (size_t)m * 192 + h * 24 + s] = val * inv;
            }
        }
    }
#undef LOAD_TILE
#undef WRITE_TILE
#undef COMPUTE_TILE
}

extern "C" void kernel_launch(void* const* d_in, const int* in_sizes, int n_in,
                              void* d_out, int out_size, void* d_ws, size_t ws_size,
                              hipStream_t stream) {
    const float* ax       = (const float*)d_in[0];
    const float* vx       = (const float*)d_in[1];
    const float* pos_k    = (const float*)d_in[2];
    const float* pos_q    = (const float*)d_in[3];
    const float* r0       = (const float*)d_in[4];
    const float* W_ak     = (const float*)d_in[5];
    const float* W_vk     = (const float*)d_in[6];
    const float* W_aq     = (const float*)d_in[7];
    const float* W_vq     = (const float*)d_in[8];
    const float* W_aval   = (const float*)d_in[9];
    const float* W_vval   = (const float*)d_in[10];
    const float* W_a2vval = (const float*)d_in[11];
    const float* W_v2aval = (const float*)d_in[12];

    ushort* Kf = (ushort*)d_ws;                         // 8*2048*128 ushort
    ushort* Qf = Kf + (size_t)NH * NN * 128;            // 8*2048*128 ushort
    ushort* Vt = Qf + (size_t)NH * NN * 128;            // 8*144*2048 ushort
    float*  Wt2 = (float*)(Vt + (size_t)NH * 144 * NN); // 32*NTASK float4
    float*  outp = (float*)d_out;

    hipLaunchKernelGGL(wtrans_kernel, dim3((NTASK * 32 + 255) / 256), dim3(256), 0, stream,
                       W_ak, W_vk, W_aq, W_vq, W_aval, W_vval, W_a2vval, W_v2aval, Wt2);
    hipLaunchKernelGGL(proj_kernel, dim3(NN / 8), dim3(1024), 0, stream,
                       ax, vx, pos_k, pos_q, Wt2, Kf, Qf, Vt);
    hipLaunchKernelGGL(attn_kernel, dim3(64 * NH), dim3(512), 0, stream,
                       Kf, Qf, Vt, pos_k, r0, outp);
}